// Round 10
// baseline (1544.941 us; speedup 1.0000x reference)
//
#include <hip/hip_runtime.h>

// ---------------------------------------------------------------------------
// LSTM: out[t] = h_t for t in [0,256);  final (c,h) appended.
//   T=256, B=128, D=1024, U=1024, 4U=4096
// Pipeline (ws ~338MB):
//   k_convert   : inputs f32 -> bf16
//   k_transpose : kernelx/kernelh f32 [1024][4096] -> W^T bf16 [4096][1024]
//   k_gemm_bf   : xz = inputs_bf @ kernelx (m97 structure, unchanged)
//   k_scan      : single launch, 256 steps, 256 blocks = 256 CUs, 1/CU;
//                 8 groups x 32 blocks (g = blk&7, XCD-local).
//                 R10: LDS double-buffered h -> stage ONCE per step (at end,
//                 after poll) into the idle buffer; 3 barriers/step (was 6);
//                 MFMA phase uninterrupted; publish vmcnt(1) = h-ack only;
//                 xz(t) waited via dedicated vmcnt(0) after zlds barrier.
// ---------------------------------------------------------------------------

typedef float  f32x4 __attribute__((ext_vector_type(4)));
typedef float  f32x2 __attribute__((ext_vector_type(2)));
typedef __bf16 bf16x8 __attribute__((ext_vector_type(8)));
typedef unsigned short us8 __attribute__((ext_vector_type(8)));
typedef unsigned short us4 __attribute__((ext_vector_type(4)));
typedef unsigned int   u32x4 __attribute__((ext_vector_type(4)));

#define TT 256
#define BB 128
#define DD 1024
#define UU 1024
#define NZ 4096

typedef __attribute__((address_space(3))) unsigned       lds_u32;
typedef const __attribute__((address_space(1))) unsigned glob_u32;

__device__ __forceinline__ unsigned short f2bf(float x) {
  union { float f; unsigned u; } v; v.f = x;
  unsigned r = v.u + 0x7fffu + ((v.u >> 16) & 1u);   // RNE
  return (unsigned short)(r >> 16);
}
__device__ __forceinline__ float bf2f(unsigned short b) {
  union { unsigned u; float f; } v; v.u = ((unsigned)b) << 16;
  return v.f;
}
__device__ __forceinline__ float sigm(float x) { return 1.f / (1.f + __expf(-x)); }
__device__ __forceinline__ float tanh_(float x) { return 1.f - 2.f / (__expf(2.f * x) + 1.f); }

// ---------------- f32 -> bf16 bulk convert (8 elems/thread)
__global__ __launch_bounds__(256) void k_convert(const float* __restrict__ in,
                                                 unsigned short* __restrict__ out,
                                                 int n8) {
  int i = blockIdx.x * 256 + threadIdx.x;
  if (i >= n8) return;
  const float4 a = *(const float4*)(in + (size_t)i * 8);
  const float4 b = *(const float4*)(in + (size_t)i * 8 + 4);
  us8 v;
  v[0] = f2bf(a.x); v[1] = f2bf(a.y); v[2] = f2bf(a.z); v[3] = f2bf(a.w);
  v[4] = f2bf(b.x); v[5] = f2bf(b.y); v[6] = f2bf(b.z); v[7] = f2bf(b.w);
  *(us8*)(out + (size_t)i * 8) = v;
}

// ---------------- transpose+convert: in f32 [1024][4096] -> out bf16 [4096][1024]
__global__ __launch_bounds__(256) void k_transpose(const float* __restrict__ in,
                                                   unsigned short* __restrict__ out) {
  __shared__ unsigned short tile[64][72];
  const int ni = blockIdx.x;
  const int ki = blockIdx.y;
  const int t = threadIdx.x;
  const int c = t & 63, r0 = t >> 6;
#pragma unroll
  for (int rr = 0; rr < 16; ++rr) {
    int r = r0 * 16 + rr;
    tile[r][c] = f2bf(in[(size_t)(ki * 64 + r) * NZ + ni * 64 + c]);
  }
  __syncthreads();
  const int kcol = t & 63, ng = t >> 6;
#pragma unroll
  for (int cc = 0; cc < 16; ++cc) {
    int n_off = ng * 16 + cc;
    out[(size_t)(ni * 64 + n_off) * DD + ki * 64 + kcol] = tile[kcol][n_off];
  }
}

// ---------------- xz = A_bf16[32768][1024] @ WxT^T, m97 structure (unchanged)
__global__ __launch_bounds__(256, 2) void k_gemm_bf(const unsigned short* __restrict__ A,
                                                    const unsigned short* __restrict__ Bt,
                                                    unsigned short* __restrict__ C) {
  __shared__ unsigned short Al[2][128 * 64];
  __shared__ unsigned short Bl[2][128 * 64];
  const int bx = blockIdx.x;
  const int wgid = (bx & 7) * 1024 + (bx >> 3);
  const int tm = wgid >> 5, tn = wgid & 31;
  const int tid = threadIdx.x;
  const int wave = tid >> 6, lane = tid & 63;
  const int wr = wave >> 1, wc = wave & 1;
  const int l15 = lane & 15, kg = lane >> 4;

  f32x4 acc[4][4] = {};   // [ni][mi]

  const int srow = tid >> 3;
  const int scol = (tid & 7) * 8;
  const unsigned sdst = tid * 8;

  auto stage = [&](int buf, int kt) {
#pragma unroll
    for (int i = 0; i < 4; ++i) {
      __builtin_amdgcn_global_load_lds(
          (glob_u32*)(A  + (size_t)(tm * 128 + i * 32 + srow) * DD + kt * 64 + scol),
          (lds_u32*)&Al[buf][i * 2048 + sdst], 16, 0, 0);
      __builtin_amdgcn_global_load_lds(
          (glob_u32*)(Bt + (size_t)(tn * 128 + i * 32 + srow) * DD + kt * 64 + scol),
          (lds_u32*)&Bl[buf][i * 2048 + sdst], 16, 0, 0);
    }
  };

  stage(0, 0);
  __syncthreads();

  for (int kt = 0; kt < 16; ++kt) {
    const int buf = kt & 1;
    if (kt < 15) stage(buf ^ 1, kt + 1);
#pragma unroll
    for (int ks = 0; ks < 2; ++ks) {
      bf16x8 af[4], bfr[4];
#pragma unroll
      for (int mi = 0; mi < 4; ++mi)
        af[mi] = *(const bf16x8*)&Al[buf][(wr * 64 + mi * 16 + l15) * 64 + ks * 32 + kg * 8];
#pragma unroll
      for (int ni = 0; ni < 4; ++ni)
        bfr[ni] = *(const bf16x8*)&Bl[buf][(wc * 64 + ni * 16 + l15) * 64 + ks * 32 + kg * 8];
#pragma unroll
      for (int mi = 0; mi < 4; ++mi)
#pragma unroll
        for (int ni = 0; ni < 4; ++ni)
          acc[ni][mi] = __builtin_amdgcn_mfma_f32_16x16x32_bf16(bfr[ni], af[mi], acc[ni][mi], 0, 0, 0);
    }
    __syncthreads();
  }

#pragma unroll
  for (int mi = 0; mi < 4; ++mi) {
    const size_t row = (size_t)tm * 128 + wr * 64 + mi * 16 + l15;
#pragma unroll
    for (int ni = 0; ni < 4; ++ni) {
      const size_t col = (size_t)tn * 128 + wc * 64 + ni * 16 + kg * 4;
      us4 v;
      v[0] = f2bf(acc[ni][mi][0]); v[1] = f2bf(acc[ni][mi][1]);
      v[2] = f2bf(acc[ni][mi][2]); v[3] = f2bf(acc[ni][mi][3]);
      *(us4*)(C + row * NZ + col) = v;
    }
  }
}

// ---------------- scan: 256 steps, double-buffered LDS h, 3 barriers/step
// Per-step VMEM ledger (FIFO oldest->newest):
//   [out(t-1)? may linger] -> publish(t): +h +out, vmcnt(1) retires h (out lingers)
//   stage(t+1): +8 stage +4 xz; vmcnt(4) retires out(t)+8 stage (xz lingers)
//   gate(t+1): vmcnt(0) retires the 4 xz (aged ~1600cy).
__global__ __launch_bounds__(256, 1) void k_scan(const float* __restrict__ init_cs,
                                                 const int* __restrict__ masks,
                                                 const unsigned short* __restrict__ WhT,
                                                 const float* __restrict__ bias,
                                                 const unsigned short* __restrict__ xz,
                                                 float* __restrict__ out,
                                                 unsigned short* __restrict__ hglob,
                                                 unsigned* __restrict__ flags) {
  __shared__ char  hlds_c[2 * 32768];           // 2 x 32KB h tiles (swizzled)
  __shared__ float zlds[4][16][33];
  __shared__ int   mlds[TT * 16 + 16];          // masks [t][er], +pad

  const int tid = threadIdx.x;
  const int wave = tid >> 6, lane = tid & 63;
  const int l15 = lane & 15, kg = lane >> 4;
  const int blk = blockIdx.x;
  const int g = blk & 7;
  const int sb = blk >> 3;
  const int u0 = sb * 32;
  const int row0 = g * 16;
  unsigned* fl = flags + g * 64;                // 256B stride per group

  // ---- Wh fragments resident in registers, pinned
  u32x4 w0[32], w1[32];
  {
    const size_t r0 = (size_t)(wave * UU + u0 + l15) * DD;
    const size_t r1 = (size_t)(wave * UU + u0 + 16 + l15) * DD;
#pragma unroll
    for (int ks = 0; ks < 32; ++ks) {
      w0[ks] = *(const u32x4*)(WhT + r0 + ks * 32 + kg * 8);
      w1[ks] = *(const u32x4*)(WhT + r1 + ks * 32 + kg * 8);
    }
#pragma unroll
    for (int ks = 0; ks < 32; ++ks) {
      asm volatile("" : "+v"(w0[ks]));
      asm volatile("" : "+v"(w1[ks]));
    }
  }

  // ---- stage masks to LDS: mlds[t*16+er] = masks[t][row0+er]
  for (int i = 0; i < 16; ++i) {
    int idx = i * 256 + tid;
    mlds[idx] = masks[(size_t)(idx >> 4) * BB + row0 + (idx & 15)];
  }
  if (tid < 16) mlds[TT * 16 + tid] = 0;

  const int er = tid >> 4;
  const int ec = (tid & 15) * 2;
  const int grow = row0 + er;
  const int guu = u0 + ec;

  float bs0[4], bs1[4];
#pragma unroll
  for (int gt = 0; gt < 4; ++gt) {
    bs0[gt] = bias[gt * UU + guu];
    bs1[gt] = bias[gt * UU + guu + 1];
  }

  float cv0 = init_cs[(size_t)grow * UU + guu];
  float cv1 = init_cs[(size_t)grow * UU + guu + 1];
  float hv0 = init_cs[(size_t)BB * UU + grow * UU + guu];
  float hv1 = init_cs[(size_t)BB * UU + grow * UU + guu + 1];

  const unsigned wswz = ((unsigned)(er & 7)) << 4;
  const unsigned hoff = (unsigned)er * 2048u + ((((unsigned)guu) * 2u) ^ wswz);

  { // publish h(0) (masked) into buf 0
    int m0 = masks[grow];                        // masks[0][grow]
    float s = m0 ? 0.f : 1.f;
    char* base = (char*)hglob + (size_t)g * 32768 + hoff;
    unsigned pv = ((unsigned)f2bf(hv1 * s) << 16) | f2bf(hv0 * s);
    *(unsigned*)base = pv;
  }
  __syncthreads();                               // full drain (prologue only)
  if (tid == 0)
    __hip_atomic_store(&fl[sb], 1u, __ATOMIC_RELAXED, __HIP_MEMORY_SCOPE_AGENT);
  { // all-wave poll
    unsigned v;
    do { v = __hip_atomic_load(&fl[lane & 31], __ATOMIC_RELAXED, __HIP_MEMORY_SCOPE_AGENT); }
    while (!__all(v >= 1));
  }

  // swizzled A-frag swizzle constant (XOR bank swizzle bits 4-6)
  const unsigned rswz = ((unsigned)(l15 & 7)) << 4;

  unsigned xz_cur[4], xz_nxt[4];

  // ---- prologue stage: h(0) -> hlds[0]; xz(0) prefetch
  {
    const char* gsrc = (const char*)hglob + (size_t)g * 32768;
    u32x4 sv[8];
#pragma unroll
    for (int i = 0; i < 8; ++i) {
      const char* ap = gsrc + (i * 256 + tid) * 16;
      asm volatile("global_load_dwordx4 %0, %1, off sc0" : "=v"(sv[i]) : "v"(ap));
    }
    {
      const char* xb = (const char*)xz + (((size_t)grow) * NZ + guu) * 2;
#pragma unroll
      for (int gt = 0; gt < 4; ++gt) {
        const void* ap = xb + gt * (UU * 2);
        asm volatile("global_load_dword %0, %1, off" : "=v"(xz_cur[gt]) : "v"(ap));
      }
    }
    asm volatile("s_waitcnt vmcnt(4)" ::: "memory");   // 8 stage retired; xz in flight
    __builtin_amdgcn_sched_barrier(0);
#pragma unroll
    for (int i = 0; i < 8; ++i)
      *(u32x4*)(hlds_c + (i * 256 + tid) * 16) = sv[i];
    asm volatile("s_waitcnt lgkmcnt(0)" ::: "memory");
    __builtin_amdgcn_sched_barrier(0);
    __builtin_amdgcn_s_barrier();
  }

  for (int t = 0; t < TT; ++t) {
    // --- MFMA phase: uninterrupted 64 MFMAs from hlds[t&1]
    const char* hb  = hlds_c + (size_t)(t & 1) * 32768;
    const char* hp0 = hb + l15 * 2048 + (((unsigned)(kg * 16 + 0)) ^ rswz);
    const char* hp1 = hb + l15 * 2048 + (((unsigned)(kg * 16 + 64)) ^ rswz);

    f32x4 acc0 = {0.f, 0.f, 0.f, 0.f};
    f32x4 acc1 = {0.f, 0.f, 0.f, 0.f};
#pragma unroll
    for (int ks = 0; ks < 32; ++ks) {
      const char* p = ((ks & 1) ? hp1 : hp0) + (ks >> 1) * 128;
      bf16x8 a = *(const bf16x8*)p;
      acc0 = __builtin_amdgcn_mfma_f32_16x16x32_bf16(a, __builtin_bit_cast(bf16x8, w0[ks]), acc0, 0, 0, 0);
      acc1 = __builtin_amdgcn_mfma_f32_16x16x32_bf16(a, __builtin_bit_cast(bf16x8, w1[ks]), acc1, 0, 0, 0);
    }

    // --- exchange gates across waves via LDS (lgkm-only barrier)
#pragma unroll
    for (int j = 0; j < 4; ++j) {
      zlds[wave][kg * 4 + j][l15] = acc0[j];
      zlds[wave][kg * 4 + j][16 + l15] = acc1[j];
    }
    asm volatile("s_waitcnt lgkmcnt(0)" ::: "memory");
    __builtin_amdgcn_sched_barrier(0);
    __builtin_amdgcn_s_barrier();

    // --- xz(t) retire (aged ~1600cy; only xz outstanding here)
    asm volatile("s_waitcnt vmcnt(0)" ::: "memory");
    __builtin_amdgcn_sched_barrier(0);

    // --- gate math
    const int mcur = mlds[t * 16 + er];
    const int mnxt = mlds[(t + 1) * 16 + er];
    float z0[4], z1[4];
#pragma unroll
    for (int gt = 0; gt < 4; ++gt) {
      z0[gt] = zlds[gt][er][ec]     + bs0[gt] + bf2f((unsigned short)(xz_cur[gt] & 0xffffu));
      z1[gt] = zlds[gt][er][ec + 1] + bs1[gt] + bf2f((unsigned short)(xz_cur[gt] >> 16));
    }
    const float sm = mcur ? 0.f : 1.f;
    cv0 *= sm; cv1 *= sm;
    {
      float ig = sigm(z0[0]), fg = sigm(z0[1]), og = sigm(z0[2]), ug = tanh_(z0[3]);
      cv0 = fg * cv0 + ig * ug;
      hv0 = og * tanh_(cv0);
    }
    {
      float ig = sigm(z1[0]), fg = sigm(z1[1]), og = sigm(z1[2]), ug = tanh_(z1[3]);
      cv1 = fg * cv1 + ig * ug;
      hv1 = og * tanh_(cv1);
    }

    // --- publish: h store (L2) then out store; vmcnt(1) = h acked only
    {
      const float sn = mnxt ? 0.f : 1.f;
      char* hdst = (char*)hglob + ((size_t)(((t + 1) & 1) * 8 + g)) * 32768 + hoff;
      unsigned pv = ((unsigned)f2bf(hv1 * sn) << 16) | f2bf(hv0 * sn);
      asm volatile("global_store_dword %0, %1, off" :: "v"(hdst), "v"(pv) : "memory");
      float* odst = out + (size_t)t * (BB * UU) + (size_t)grow * UU + guu;
      f32x2 ov = {hv0, hv1};
      asm volatile("global_store_dwordx2 %0, %1, off" :: "v"(odst), "v"(ov) : "memory");
    }
    asm volatile("s_waitcnt vmcnt(1)" ::: "memory");
    __builtin_amdgcn_sched_barrier(0);
    __builtin_amdgcn_s_barrier();                // all waves' h stores acked
    if (tid == 0)
      __hip_atomic_store(&fl[sb], (unsigned)(t + 2), __ATOMIC_RELAXED, __HIP_MEMORY_SCOPE_AGENT);

    if (t + 1 < TT) {
      { // all-wave poll for h(t+1)
        const unsigned tgt = (unsigned)(t + 2);
        unsigned v;
        do { v = __hip_atomic_load(&fl[lane & 31], __ATOMIC_RELAXED, __HIP_MEMORY_SCOPE_AGENT); }
        while (!__all(v >= tgt));
      }
      // stage h(t+1) -> hlds[(t+1)&1]; xz(t+1) prefetch (newest in FIFO)
      const char* gsrc = (const char*)hglob + ((size_t)(((t + 1) & 1) * 8 + g)) * 32768;
      u32x4 sv[8];
#pragma unroll
      for (int i = 0; i < 8; ++i) {
        const char* ap = gsrc + (i * 256 + tid) * 16;
        asm volatile("global_load_dwordx4 %0, %1, off sc0" : "=v"(sv[i]) : "v"(ap));
      }
      {
        const char* xb = (const char*)xz + (((size_t)((t + 1) * BB + grow)) * NZ + guu) * 2;
#pragma unroll
        for (int gt = 0; gt < 4; ++gt) {
          const void* ap = xb + gt * (UU * 2);
          asm volatile("global_load_dword %0, %1, off" : "=v"(xz_nxt[gt]) : "v"(ap));
        }
      }
      asm volatile("s_waitcnt vmcnt(4)" ::: "memory");   // out(t)+8 stage retired
      __builtin_amdgcn_sched_barrier(0);
      char* ldst = hlds_c + (size_t)((t + 1) & 1) * 32768;
#pragma unroll
      for (int i = 0; i < 8; ++i)
        *(u32x4*)(ldst + (i * 256 + tid) * 16) = sv[i];
      asm volatile("s_waitcnt lgkmcnt(0)" ::: "memory");
      __builtin_amdgcn_sched_barrier(0);
      __builtin_amdgcn_s_barrier();

#pragma unroll
      for (int gt = 0; gt < 4; ++gt) xz_cur[gt] = xz_nxt[gt];
    }
  }

  // final states: [c ; h] appended after out
  float* so = out + (size_t)TT * BB * UU;
  *(f32x2*)(so + (size_t)grow * UU + guu) = (f32x2){cv0, cv1};
  *(f32x2*)(so + (size_t)BB * UU + grow * UU + guu) = (f32x2){hv0, hv1};
}

// ---------------------------------------------------------------------------
extern "C" void kernel_launch(void* const* d_in, const int* in_sizes, int n_in,
                              void* d_out, int out_size, void* d_ws, size_t ws_size,
                              hipStream_t stream) {
  const float* inputs  = (const float*)d_in[0];  // [256][128][1024]
  const float* states  = (const float*)d_in[1];  // [2][128][1024]
  const int*   masks   = (const int*)d_in[2];    // [256][128]
  const float* kernelx = (const float*)d_in[3];  // [1024][4096]
  const float* kernelh = (const float*)d_in[4];  // [1024][4096]
  const float* bias    = (const float*)d_in[5];  // [4096]
  float* out = (float*)d_out;
  char* ws = (char*)d_ws;

  unsigned* flags       = (unsigned*)ws;                                 // 2KB
  unsigned short* hglob = (unsigned short*)(ws + 65536);                 // 512KB
  unsigned short* WhT   = (unsigned short*)(ws + (size_t)2  * 1048576);  // 8MB
  unsigned short* WxT   = (unsigned short*)(ws + (size_t)10 * 1048576);  // 8MB
  unsigned short* Abf   = (unsigned short*)(ws + (size_t)18 * 1048576);  // 64MB
  unsigned short* xzbig = (unsigned short*)(ws + (size_t)82 * 1048576);  // 256MB

  k_transpose<<<dim3(64, 16), dim3(256), 0, stream>>>(kernelx, WxT);
  k_transpose<<<dim3(64, 16), dim3(256), 0, stream>>>(kernelh, WhT);
  k_convert<<<dim3(16384), dim3(256), 0, stream>>>(inputs, Abf, (TT * BB * DD) / 8);
  k_gemm_bf<<<dim3(8192), dim3(256), 0, stream>>>(Abf, WxT, xzbig);
  hipMemsetAsync(flags, 0, 2048, stream);
  k_scan<<<dim3(256), dim3(256), 0, stream>>>(states, masks, WhT, bias, xzbig,
                                              out, hglob, flags);
}

// Round 11
// 1363.950 us; speedup vs baseline: 1.1327x; 1.1327x over previous
//
#include <hip/hip_runtime.h>

// ---------------------------------------------------------------------------
// LSTM: out[t] = h_t for t in [0,256);  final (c,h) appended.
//   T=256, B=128, D=1024, U=1024, 4U=4096
// Pipeline (ws ~338MB):
//   k_convert   : inputs f32 -> bf16
//   k_transpose : kernelx/kernelh f32 [1024][4096] -> W^T bf16 [4096][1024]
//   k_gemm_bf   : xz = inputs_bf @ kernelx (m97 structure, unchanged)
//   k_scan      : single launch, 256 steps, 256 blocks = 256 CUs, 1/CU;
//                 8 groups x 32 blocks (g = blk&7, XCD-local).
//                 R11 = R8 quarter-pipelined staging (proven best) +
//                 corrected xz-in-FIFO counts vmcnt(10/8/6/4) +
//                 lgkm-only zlds barrier + counted publish vmcnt(1) +
//                 wave0-only poll + release barrier.
// Per-step VMEM ledger (FIFO oldest->newest), entering step: <=1 (out(t-1)):
//   issue s1..s8 (stage h(t)), x1..x4 (xz(t+1))      -> outstanding <= 13
//   Q0 vmcnt(10): retires [out,]s1,s2   Q1 vmcnt(8): s3,s4
//   Q2 vmcnt(6):  s5,s6                 Q3 vmcnt(4): s7,s8   (xz in flight)
//   publish: +h +out -> 6; vmcnt(1) retires x1..x4,h; out lingers.
// ---------------------------------------------------------------------------

typedef float  f32x4 __attribute__((ext_vector_type(4)));
typedef float  f32x2 __attribute__((ext_vector_type(2)));
typedef __bf16 bf16x8 __attribute__((ext_vector_type(8)));
typedef unsigned short us8 __attribute__((ext_vector_type(8)));
typedef unsigned short us4 __attribute__((ext_vector_type(4)));
typedef unsigned int   u32x4 __attribute__((ext_vector_type(4)));

#define TT 256
#define BB 128
#define DD 1024
#define UU 1024
#define NZ 4096

typedef __attribute__((address_space(3))) unsigned       lds_u32;
typedef const __attribute__((address_space(1))) unsigned glob_u32;

__device__ __forceinline__ unsigned short f2bf(float x) {
  union { float f; unsigned u; } v; v.f = x;
  unsigned r = v.u + 0x7fffu + ((v.u >> 16) & 1u);   // RNE
  return (unsigned short)(r >> 16);
}
__device__ __forceinline__ float bf2f(unsigned short b) {
  union { unsigned u; float f; } v; v.u = ((unsigned)b) << 16;
  return v.f;
}
__device__ __forceinline__ float sigm(float x) { return 1.f / (1.f + __expf(-x)); }
__device__ __forceinline__ float tanh_(float x) { return 1.f - 2.f / (__expf(2.f * x) + 1.f); }

// ---------------- f32 -> bf16 bulk convert (8 elems/thread)
__global__ __launch_bounds__(256) void k_convert(const float* __restrict__ in,
                                                 unsigned short* __restrict__ out,
                                                 int n8) {
  int i = blockIdx.x * 256 + threadIdx.x;
  if (i >= n8) return;
  const float4 a = *(const float4*)(in + (size_t)i * 8);
  const float4 b = *(const float4*)(in + (size_t)i * 8 + 4);
  us8 v;
  v[0] = f2bf(a.x); v[1] = f2bf(a.y); v[2] = f2bf(a.z); v[3] = f2bf(a.w);
  v[4] = f2bf(b.x); v[5] = f2bf(b.y); v[6] = f2bf(b.z); v[7] = f2bf(b.w);
  *(us8*)(out + (size_t)i * 8) = v;
}

// ---------------- transpose+convert: in f32 [1024][4096] -> out bf16 [4096][1024]
__global__ __launch_bounds__(256) void k_transpose(const float* __restrict__ in,
                                                   unsigned short* __restrict__ out) {
  __shared__ unsigned short tile[64][72];
  const int ni = blockIdx.x;
  const int ki = blockIdx.y;
  const int t = threadIdx.x;
  const int c = t & 63, r0 = t >> 6;
#pragma unroll
  for (int rr = 0; rr < 16; ++rr) {
    int r = r0 * 16 + rr;
    tile[r][c] = f2bf(in[(size_t)(ki * 64 + r) * NZ + ni * 64 + c]);
  }
  __syncthreads();
  const int kcol = t & 63, ng = t >> 6;
#pragma unroll
  for (int cc = 0; cc < 16; ++cc) {
    int n_off = ng * 16 + cc;
    out[(size_t)(ni * 64 + n_off) * DD + ki * 64 + kcol] = tile[kcol][n_off];
  }
}

// ---------------- xz = A_bf16[32768][1024] @ WxT^T, m97 structure (unchanged)
__global__ __launch_bounds__(256, 2) void k_gemm_bf(const unsigned short* __restrict__ A,
                                                    const unsigned short* __restrict__ Bt,
                                                    unsigned short* __restrict__ C) {
  __shared__ unsigned short Al[2][128 * 64];
  __shared__ unsigned short Bl[2][128 * 64];
  const int bx = blockIdx.x;
  const int wgid = (bx & 7) * 1024 + (bx >> 3);
  const int tm = wgid >> 5, tn = wgid & 31;
  const int tid = threadIdx.x;
  const int wave = tid >> 6, lane = tid & 63;
  const int wr = wave >> 1, wc = wave & 1;
  const int l15 = lane & 15, kg = lane >> 4;

  f32x4 acc[4][4] = {};   // [ni][mi]

  const int srow = tid >> 3;
  const int scol = (tid & 7) * 8;
  const unsigned sdst = tid * 8;

  auto stage = [&](int buf, int kt) {
#pragma unroll
    for (int i = 0; i < 4; ++i) {
      __builtin_amdgcn_global_load_lds(
          (glob_u32*)(A  + (size_t)(tm * 128 + i * 32 + srow) * DD + kt * 64 + scol),
          (lds_u32*)&Al[buf][i * 2048 + sdst], 16, 0, 0);
      __builtin_amdgcn_global_load_lds(
          (glob_u32*)(Bt + (size_t)(tn * 128 + i * 32 + srow) * DD + kt * 64 + scol),
          (lds_u32*)&Bl[buf][i * 2048 + sdst], 16, 0, 0);
    }
  };

  stage(0, 0);
  __syncthreads();

  for (int kt = 0; kt < 16; ++kt) {
    const int buf = kt & 1;
    if (kt < 15) stage(buf ^ 1, kt + 1);
#pragma unroll
    for (int ks = 0; ks < 2; ++ks) {
      bf16x8 af[4], bfr[4];
#pragma unroll
      for (int mi = 0; mi < 4; ++mi)
        af[mi] = *(const bf16x8*)&Al[buf][(wr * 64 + mi * 16 + l15) * 64 + ks * 32 + kg * 8];
#pragma unroll
      for (int ni = 0; ni < 4; ++ni)
        bfr[ni] = *(const bf16x8*)&Bl[buf][(wc * 64 + ni * 16 + l15) * 64 + ks * 32 + kg * 8];
#pragma unroll
      for (int mi = 0; mi < 4; ++mi)
#pragma unroll
        for (int ni = 0; ni < 4; ++ni)
          acc[ni][mi] = __builtin_amdgcn_mfma_f32_16x16x32_bf16(bfr[ni], af[mi], acc[ni][mi], 0, 0, 0);
    }
    __syncthreads();
  }

#pragma unroll
  for (int mi = 0; mi < 4; ++mi) {
    const size_t row = (size_t)tm * 128 + wr * 64 + mi * 16 + l15;
#pragma unroll
    for (int ni = 0; ni < 4; ++ni) {
      const size_t col = (size_t)tn * 128 + wc * 64 + ni * 16 + kg * 4;
      us4 v;
      v[0] = f2bf(acc[ni][mi][0]); v[1] = f2bf(acc[ni][mi][1]);
      v[2] = f2bf(acc[ni][mi][2]); v[3] = f2bf(acc[ni][mi][3]);
      *(us4*)(C + row * NZ + col) = v;
    }
  }
}

// ---------------- scan: R8 quarter pipeline with corrected counts
#define SCAN_QUARTER(Q, VMSTR)                                                  \
  {                                                                             \
    asm volatile("s_waitcnt " VMSTR ::: "memory");                              \
    __builtin_amdgcn_sched_barrier(0);                                          \
    *(u32x4*)(hlds_c + sbase + (Q) * 512)         = sv[(Q) * 2];                \
    *(u32x4*)(hlds_c + sbase + 16384 + (Q) * 512) = sv[(Q) * 2 + 1];            \
    asm volatile("s_waitcnt lgkmcnt(0)" ::: "memory");                          \
    __builtin_amdgcn_sched_barrier(0);                                          \
    __builtin_amdgcn_s_barrier();                                               \
    _Pragma("unroll")                                                           \
    for (int ks = (Q) * 8; ks < (Q) * 8 + 8; ++ks) {                            \
      const char* p = ((ks & 1) ? hp1 : hp0) + (ks >> 1) * 128;                 \
      bf16x8 a = *(const bf16x8*)p;                                             \
      acc0 = __builtin_amdgcn_mfma_f32_16x16x32_bf16(a, __builtin_bit_cast(bf16x8, w0[ks]), acc0, 0, 0, 0); \
      acc1 = __builtin_amdgcn_mfma_f32_16x16x32_bf16(a, __builtin_bit_cast(bf16x8, w1[ks]), acc1, 0, 0, 0); \
    }                                                                           \
  }

__global__ __launch_bounds__(256, 1) void k_scan(const float* __restrict__ init_cs,
                                                 const int* __restrict__ masks,
                                                 const unsigned short* __restrict__ WhT,
                                                 const float* __restrict__ bias,
                                                 const unsigned short* __restrict__ xz,
                                                 float* __restrict__ out,
                                                 unsigned short* __restrict__ hglob,
                                                 unsigned* __restrict__ flags) {
  __shared__ char  hlds_c[32768];               // 32KB h tile (swizzled layout)
  __shared__ float zlds[4][16][33];
  __shared__ int   mlds[TT * 16 + 16];          // masks [t][er], +pad

  const int tid = threadIdx.x;
  const int wave = tid >> 6, lane = tid & 63;
  const int l15 = lane & 15, kg = lane >> 4;
  const int blk = blockIdx.x;
  const int g = blk & 7;
  const int sb = blk >> 3;
  const int u0 = sb * 32;
  const int row0 = g * 16;
  unsigned* fl = flags + g * 64;                // 256B stride per group

  // ---- Wh fragments resident in registers, pinned
  u32x4 w0[32], w1[32];
  {
    const size_t r0 = (size_t)(wave * UU + u0 + l15) * DD;
    const size_t r1 = (size_t)(wave * UU + u0 + 16 + l15) * DD;
#pragma unroll
    for (int ks = 0; ks < 32; ++ks) {
      w0[ks] = *(const u32x4*)(WhT + r0 + ks * 32 + kg * 8);
      w1[ks] = *(const u32x4*)(WhT + r1 + ks * 32 + kg * 8);
    }
#pragma unroll
    for (int ks = 0; ks < 32; ++ks) {
      asm volatile("" : "+v"(w0[ks]));
      asm volatile("" : "+v"(w1[ks]));
    }
  }

  // ---- stage masks to LDS: mlds[t*16+er] = masks[t][row0+er]
  for (int i = 0; i < 16; ++i) {
    int idx = i * 256 + tid;
    mlds[idx] = masks[(size_t)(idx >> 4) * BB + row0 + (idx & 15)];
  }
  if (tid < 16) mlds[TT * 16 + tid] = 0;

  const int er = tid >> 4;
  const int ec = (tid & 15) * 2;
  const int grow = row0 + er;
  const int guu = u0 + ec;

  float bs0[4], bs1[4];
#pragma unroll
  for (int gt = 0; gt < 4; ++gt) {
    bs0[gt] = bias[gt * UU + guu];
    bs1[gt] = bias[gt * UU + guu + 1];
  }

  float cv0 = init_cs[(size_t)grow * UU + guu];
  float cv1 = init_cs[(size_t)grow * UU + guu + 1];
  float hv0 = init_cs[(size_t)BB * UU + grow * UU + guu];
  float hv1 = init_cs[(size_t)BB * UU + grow * UU + guu + 1];

  const unsigned wswz = ((unsigned)(er & 7)) << 4;
  const unsigned hoff = (unsigned)er * 2048u + ((((unsigned)guu) * 2u) ^ wswz);

  { // publish h(0) (masked) into buf 0
    int m0 = masks[grow];                        // masks[0][grow]
    float s = m0 ? 0.f : 1.f;
    char* base = (char*)hglob + (size_t)g * 32768 + hoff;
    unsigned pv = ((unsigned)f2bf(hv1 * s) << 16) | f2bf(hv0 * s);
    *(unsigned*)base = pv;
  }
  __syncthreads();                               // full drain (prologue only)
  if (tid == 0)
    __hip_atomic_store(&fl[sb], 1u, __ATOMIC_RELAXED, __HIP_MEMORY_SCOPE_AGENT);
  if (wave == 0) {                               // wave0-only poll
    unsigned v;
    do { v = __hip_atomic_load(&fl[lane & 31], __ATOMIC_RELAXED, __HIP_MEMORY_SCOPE_AGENT); }
    while (!__all(v >= 1));
  }
  __syncthreads();

  // swizzled A-frag base pointers (XOR bank swizzle bits 4-6)
  const unsigned rswz = ((unsigned)(l15 & 7)) << 4;
  const char* hp0 = hlds_c + l15 * 2048 + (((unsigned)(kg * 16 + 0)) ^ rswz);
  const char* hp1 = hlds_c + l15 * 2048 + (((unsigned)(kg * 16 + 64)) ^ rswz);

  // staging address: row = tid>>5 (j=0) / 8+(tid>>5) (j=1), 16B chunk tid&31
  const unsigned sbase = ((unsigned)(tid >> 5)) * 2048u + ((unsigned)(tid & 31)) * 16u;

  // xz(0): dedicated load + full drain (one-time; keeps per-step ledger exact)
  unsigned xz_cur[4], xz_nxt[4];
  {
    const char* xb = (const char*)xz + (((size_t)grow) * NZ + guu) * 2;
#pragma unroll
    for (int gt = 0; gt < 4; ++gt) {
      const void* ap = xb + gt * (UU * 2);
      asm volatile("global_load_dword %0, %1, off" : "=v"(xz_cur[gt]) : "v"(ap));
    }
    asm volatile("s_waitcnt vmcnt(0)" ::: "memory");
    __builtin_amdgcn_sched_barrier(0);
  }

  for (int t = 0; t < TT; ++t) {
    const char* gsrc = (const char*)hglob + ((size_t)((t & 1) * 8 + g)) * 32768;

    // --- issue 8 stage loads (oldest), quarter order
    u32x4 sv[8];
#pragma unroll
    for (int q = 0; q < 4; ++q) {
#pragma unroll
      for (int j = 0; j < 2; ++j) {
        const char* ap = gsrc + sbase + j * 16384 + q * 512;
        asm volatile("global_load_dwordx4 %0, %1, off sc0" : "=v"(sv[q * 2 + j]) : "v"(ap));
      }
    }
    // --- issue xz(t+1) (newest; retired by this step's publish vmcnt(1))
    {
      const int t1 = (t + 1 < TT) ? t + 1 : t;
      const char* xb = (const char*)xz + (((size_t)(t1 * BB + grow)) * NZ + guu) * 2;
#pragma unroll
      for (int gt = 0; gt < 4; ++gt) {
        const void* ap = xb + gt * (UU * 2);
        asm volatile("global_load_dword %0, %1, off" : "=v"(xz_nxt[gt]) : "v"(ap));
      }
    }

    f32x4 acc0 = {0.f, 0.f, 0.f, 0.f};
    f32x4 acc1 = {0.f, 0.f, 0.f, 0.f};

    SCAN_QUARTER(0, "vmcnt(10)")
    SCAN_QUARTER(1, "vmcnt(8)")
    SCAN_QUARTER(2, "vmcnt(6)")
    SCAN_QUARTER(3, "vmcnt(4)")   // all stage retired; 4 xz in flight

    // --- exchange gates across waves via LDS (lgkm-only barrier)
#pragma unroll
    for (int j = 0; j < 4; ++j) {
      zlds[wave][kg * 4 + j][l15] = acc0[j];
      zlds[wave][kg * 4 + j][16 + l15] = acc1[j];
    }
    asm volatile("s_waitcnt lgkmcnt(0)" ::: "memory");
    __builtin_amdgcn_sched_barrier(0);
    __builtin_amdgcn_s_barrier();
    __builtin_amdgcn_sched_barrier(0);

    // --- gate math (xz_cur retired by previous step's publish vmcnt(1))
    const int mcur = mlds[t * 16 + er];
    const int mnxt = mlds[(t + 1) * 16 + er];
    float z0[4], z1[4];
#pragma unroll
    for (int gt = 0; gt < 4; ++gt) {
      z0[gt] = zlds[gt][er][ec]     + bs0[gt] + bf2f((unsigned short)(xz_cur[gt] & 0xffffu));
      z1[gt] = zlds[gt][er][ec + 1] + bs1[gt] + bf2f((unsigned short)(xz_cur[gt] >> 16));
    }
    const float sm = mcur ? 0.f : 1.f;
    cv0 *= sm; cv1 *= sm;
    {
      float ig = sigm(z0[0]), fg = sigm(z0[1]), og = sigm(z0[2]), ug = tanh_(z0[3]);
      cv0 = fg * cv0 + ig * ug;
      hv0 = og * tanh_(cv0);
    }
    {
      float ig = sigm(z1[0]), fg = sigm(z1[1]), og = sigm(z1[2]), ug = tanh_(z1[3]);
      cv1 = fg * cv1 + ig * ug;
      hv1 = og * tanh_(cv1);
    }

    // --- publish: h store then out store; vmcnt(1) retires xz(t+1)+h
    {
      const float sn = mnxt ? 0.f : 1.f;
      char* hdst = (char*)hglob + ((size_t)(((t + 1) & 1) * 8 + g)) * 32768 + hoff;
      unsigned pv = ((unsigned)f2bf(hv1 * sn) << 16) | f2bf(hv0 * sn);
      asm volatile("global_store_dword %0, %1, off" :: "v"(hdst), "v"(pv) : "memory");
      float* odst = out + (size_t)t * (BB * UU) + (size_t)grow * UU + guu;
      f32x2 ov = {hv0, hv1};
      asm volatile("global_store_dwordx2 %0, %1, off" :: "v"(odst), "v"(ov) : "memory");
    }
    asm volatile("s_waitcnt vmcnt(1)" ::: "memory");
    __builtin_amdgcn_sched_barrier(0);
    __builtin_amdgcn_s_barrier();                // all waves' h stores acked
    if (tid == 0)
      __hip_atomic_store(&fl[sb], (unsigned)(t + 2), __ATOMIC_RELAXED, __HIP_MEMORY_SCOPE_AGENT);
    if (wave == 0) {                             // wave0-only poll
      const unsigned tgt = (unsigned)(t + 2);
      unsigned v;
      do { v = __hip_atomic_load(&fl[lane & 31], __ATOMIC_RELAXED, __HIP_MEMORY_SCOPE_AGENT); }
      while (!__all(v >= tgt));
    }
    __builtin_amdgcn_s_barrier();                // release

#pragma unroll
    for (int gt = 0; gt < 4; ++gt) xz_cur[gt] = xz_nxt[gt];
  }

  // final states: [c ; h] appended after out
  float* so = out + (size_t)TT * BB * UU;
  *(f32x2*)(so + (size_t)grow * UU + guu) = (f32x2){cv0, cv1};
  *(f32x2*)(so + (size_t)BB * UU + grow * UU + guu) = (f32x2){hv0, hv1};
}

// ---------------------------------------------------------------------------
extern "C" void kernel_launch(void* const* d_in, const int* in_sizes, int n_in,
                              void* d_out, int out_size, void* d_ws, size_t ws_size,
                              hipStream_t stream) {
  const float* inputs  = (const float*)d_in[0];  // [256][128][1024]
  const float* states  = (const float*)d_in[1];  // [2][128][1024]
  const int*   masks   = (const int*)d_in[2];    // [256][128]
  const float* kernelx = (const float*)d_in[3];  // [1024][4096]
  const float* kernelh = (const float*)d_in[4];  // [1024][4096]
  const float* bias    = (const float*)d_in[5];  // [4096]
  float* out = (float*)d_out;
  char* ws = (char*)d_ws;

  unsigned* flags       = (unsigned*)ws;                                 // 2KB
  unsigned short* hglob = (unsigned short*)(ws + 65536);                 // 512KB
  unsigned short* WhT   = (unsigned short*)(ws + (size_t)2  * 1048576);  // 8MB
  unsigned short* WxT   = (unsigned short*)(ws + (size_t)10 * 1048576);  // 8MB
  unsigned short* Abf   = (unsigned short*)(ws + (size_t)18 * 1048576);  // 64MB
  unsigned short* xzbig = (unsigned short*)(ws + (size_t)82 * 1048576);  // 256MB

  k_transpose<<<dim3(64, 16), dim3(256), 0, stream>>>(kernelx, WxT);
  k_transpose<<<dim3(64, 16), dim3(256), 0, stream>>>(kernelh, WhT);
  k_convert<<<dim3(16384), dim3(256), 0, stream>>>(inputs, Abf, (TT * BB * DD) / 8);
  k_gemm_bf<<<dim3(8192), dim3(256), 0, stream>>>(Abf, WxT, xzbig);
  hipMemsetAsync(flags, 0, 2048, stream);
  k_scan<<<dim3(256), dim3(256), 0, stream>>>(states, masks, WhT, bias, xzbig,
                                              out, hglob, flags);
}

// Round 12
// 1202.514 us; speedup vs baseline: 1.2848x; 1.1342x over previous
//
#include <hip/hip_runtime.h>

// ---------------------------------------------------------------------------
// LSTM: out[t] = h_t for t in [0,256);  final (c,h) appended.
//   T=256, B=128, D=1024, U=1024, 4U=4096
// Pipeline (ws ~338MB):
//   k_convert   : inputs f32 -> bf16
//   k_transpose : kernelx/kernelh f32 [1024][4096] -> W^T bf16 [4096][1024]
//   k_gemm_bf   : xz = inputs_bf @ kernelx (m97 structure)
//   k_scan      : single launch, 256 steps, 256 blocks = 256 CUs, 1/CU;
//                 8 groups x 32 blocks (g = blk&7, XCD-local).
//                 R8 schedule (measured optimum): quarter-pipelined h staging
//                 (counted vmcnt, raw barriers; MFMA q hides stage of q+1..3),
//                 mid-step xz loads drained at the zlds sync, counted publish
//                 (h-store acked via vmcnt(1); out-store in flight across the
//                 step boundary), distributed flag barrier with wave0 poll.
// ---------------------------------------------------------------------------

typedef float  f32x4 __attribute__((ext_vector_type(4)));
typedef float  f32x2 __attribute__((ext_vector_type(2)));
typedef __bf16 bf16x8 __attribute__((ext_vector_type(8)));
typedef unsigned short us8 __attribute__((ext_vector_type(8)));
typedef unsigned short us4 __attribute__((ext_vector_type(4)));
typedef unsigned int   u32x4 __attribute__((ext_vector_type(4)));

#define TT 256
#define BB 128
#define DD 1024
#define UU 1024
#define NZ 4096

typedef __attribute__((address_space(3))) unsigned       lds_u32;
typedef const __attribute__((address_space(1))) unsigned glob_u32;

__device__ __forceinline__ unsigned short f2bf(float x) {
  union { float f; unsigned u; } v; v.f = x;
  unsigned r = v.u + 0x7fffu + ((v.u >> 16) & 1u);   // RNE
  return (unsigned short)(r >> 16);
}
__device__ __forceinline__ float bf2f(unsigned short b) {
  union { unsigned u; float f; } v; v.u = ((unsigned)b) << 16;
  return v.f;
}
__device__ __forceinline__ float sigm(float x) { return 1.f / (1.f + __expf(-x)); }
__device__ __forceinline__ float tanh_(float x) { return 1.f - 2.f / (__expf(2.f * x) + 1.f); }

// ---------------- f32 -> bf16 bulk convert (8 elems/thread)
__global__ __launch_bounds__(256) void k_convert(const float* __restrict__ in,
                                                 unsigned short* __restrict__ out,
                                                 int n8) {
  int i = blockIdx.x * 256 + threadIdx.x;
  if (i >= n8) return;
  const float4 a = *(const float4*)(in + (size_t)i * 8);
  const float4 b = *(const float4*)(in + (size_t)i * 8 + 4);
  us8 v;
  v[0] = f2bf(a.x); v[1] = f2bf(a.y); v[2] = f2bf(a.z); v[3] = f2bf(a.w);
  v[4] = f2bf(b.x); v[5] = f2bf(b.y); v[6] = f2bf(b.z); v[7] = f2bf(b.w);
  *(us8*)(out + (size_t)i * 8) = v;
}

// ---------------- transpose+convert: in f32 [1024][4096] -> out bf16 [4096][1024]
__global__ __launch_bounds__(256) void k_transpose(const float* __restrict__ in,
                                                   unsigned short* __restrict__ out) {
  __shared__ unsigned short tile[64][72];
  const int ni = blockIdx.x;
  const int ki = blockIdx.y;
  const int t = threadIdx.x;
  const int c = t & 63, r0 = t >> 6;
#pragma unroll
  for (int rr = 0; rr < 16; ++rr) {
    int r = r0 * 16 + rr;
    tile[r][c] = f2bf(in[(size_t)(ki * 64 + r) * NZ + ni * 64 + c]);
  }
  __syncthreads();
  const int kcol = t & 63, ng = t >> 6;
#pragma unroll
  for (int cc = 0; cc < 16; ++cc) {
    int n_off = ng * 16 + cc;
    out[(size_t)(ni * 64 + n_off) * DD + ki * 64 + kcol] = tile[kcol][n_off];
  }
}

// ---------------- xz = A_bf16[32768][1024] @ WxT^T, m97 structure
__global__ __launch_bounds__(256, 2) void k_gemm_bf(const unsigned short* __restrict__ A,
                                                    const unsigned short* __restrict__ Bt,
                                                    unsigned short* __restrict__ C) {
  __shared__ unsigned short Al[2][128 * 64];
  __shared__ unsigned short Bl[2][128 * 64];
  const int bx = blockIdx.x;
  const int wgid = (bx & 7) * 1024 + (bx >> 3);
  const int tm = wgid >> 5, tn = wgid & 31;
  const int tid = threadIdx.x;
  const int wave = tid >> 6, lane = tid & 63;
  const int wr = wave >> 1, wc = wave & 1;
  const int l15 = lane & 15, kg = lane >> 4;

  f32x4 acc[4][4] = {};   // [ni][mi]

  const int srow = tid >> 3;
  const int scol = (tid & 7) * 8;
  const unsigned sdst = tid * 8;

  auto stage = [&](int buf, int kt) {
#pragma unroll
    for (int i = 0; i < 4; ++i) {
      __builtin_amdgcn_global_load_lds(
          (glob_u32*)(A  + (size_t)(tm * 128 + i * 32 + srow) * DD + kt * 64 + scol),
          (lds_u32*)&Al[buf][i * 2048 + sdst], 16, 0, 0);
      __builtin_amdgcn_global_load_lds(
          (glob_u32*)(Bt + (size_t)(tn * 128 + i * 32 + srow) * DD + kt * 64 + scol),
          (lds_u32*)&Bl[buf][i * 2048 + sdst], 16, 0, 0);
    }
  };

  stage(0, 0);
  __syncthreads();

  for (int kt = 0; kt < 16; ++kt) {
    const int buf = kt & 1;
    if (kt < 15) stage(buf ^ 1, kt + 1);
#pragma unroll
    for (int ks = 0; ks < 2; ++ks) {
      bf16x8 af[4], bfr[4];
#pragma unroll
      for (int mi = 0; mi < 4; ++mi)
        af[mi] = *(const bf16x8*)&Al[buf][(wr * 64 + mi * 16 + l15) * 64 + ks * 32 + kg * 8];
#pragma unroll
      for (int ni = 0; ni < 4; ++ni)
        bfr[ni] = *(const bf16x8*)&Bl[buf][(wc * 64 + ni * 16 + l15) * 64 + ks * 32 + kg * 8];
#pragma unroll
      for (int mi = 0; mi < 4; ++mi)
#pragma unroll
        for (int ni = 0; ni < 4; ++ni)
          acc[ni][mi] = __builtin_amdgcn_mfma_f32_16x16x32_bf16(bfr[ni], af[mi], acc[ni][mi], 0, 0, 0);
    }
    __syncthreads();
  }

#pragma unroll
  for (int mi = 0; mi < 4; ++mi) {
    const size_t row = (size_t)tm * 128 + wr * 64 + mi * 16 + l15;
#pragma unroll
    for (int ni = 0; ni < 4; ++ni) {
      const size_t col = (size_t)tn * 128 + wc * 64 + ni * 16 + kg * 4;
      us4 v;
      v[0] = f2bf(acc[ni][mi][0]); v[1] = f2bf(acc[ni][mi][1]);
      v[2] = f2bf(acc[ni][mi][2]); v[3] = f2bf(acc[ni][mi][3]);
      *(us4*)(C + row * NZ + col) = v;
    }
  }
}

// ---------------- scan: 256 steps, quarter-pipelined staging + counted publish
// One quarter = k-bytes [q*512, q*512+512) of all 16 rows (8KB).
// sv[2q],sv[2q+1] = rows 0-7 / 8-15 portions of quarter q.
#define SCAN_QUARTER(Q, VMSTR)                                                  \
  {                                                                             \
    asm volatile("s_waitcnt " VMSTR ::: "memory");                              \
    __builtin_amdgcn_sched_barrier(0);                                          \
    *(u32x4*)(hlds_c + sbase + (Q) * 512)         = sv[(Q) * 2];                \
    *(u32x4*)(hlds_c + sbase + 16384 + (Q) * 512) = sv[(Q) * 2 + 1];            \
    asm volatile("s_waitcnt lgkmcnt(0)" ::: "memory");                          \
    __builtin_amdgcn_sched_barrier(0);                                          \
    __builtin_amdgcn_s_barrier();                                               \
    _Pragma("unroll")                                                           \
    for (int ks = (Q) * 8; ks < (Q) * 8 + 8; ++ks) {                            \
      const char* p = ((ks & 1) ? hp1 : hp0) + (ks >> 1) * 128;                 \
      bf16x8 a = *(const bf16x8*)p;                                             \
      acc0 = __builtin_amdgcn_mfma_f32_16x16x32_bf16(a, __builtin_bit_cast(bf16x8, w0[ks]), acc0, 0, 0, 0); \
      acc1 = __builtin_amdgcn_mfma_f32_16x16x32_bf16(a, __builtin_bit_cast(bf16x8, w1[ks]), acc1, 0, 0, 0); \
    }                                                                           \
  }

__global__ __launch_bounds__(256, 1) void k_scan(const float* __restrict__ init_cs,
                                                 const int* __restrict__ masks,
                                                 const unsigned short* __restrict__ WhT,
                                                 const float* __restrict__ bias,
                                                 const unsigned short* __restrict__ xz,
                                                 float* __restrict__ out,
                                                 unsigned short* __restrict__ hglob,
                                                 unsigned* __restrict__ flags) {
  __shared__ char  hlds_c[32768];               // 32KB h tile (swizzled layout)
  __shared__ float zlds[4][16][33];
  __shared__ int   mlds[TT * 16 + 16];          // masks [t][er], +pad

  const int tid = threadIdx.x;
  const int wave = tid >> 6, lane = tid & 63;
  const int l15 = lane & 15, kg = lane >> 4;
  const int blk = blockIdx.x;
  const int g = blk & 7;
  const int sb = blk >> 3;
  const int u0 = sb * 32;
  const int row0 = g * 16;
  unsigned* fl = flags + g * 64;                // 256B stride per group

  // ---- Wh fragments resident in registers, pinned
  u32x4 w0[32], w1[32];
  {
    const size_t r0 = (size_t)(wave * UU + u0 + l15) * DD;
    const size_t r1 = (size_t)(wave * UU + u0 + 16 + l15) * DD;
#pragma unroll
    for (int ks = 0; ks < 32; ++ks) {
      w0[ks] = *(const u32x4*)(WhT + r0 + ks * 32 + kg * 8);
      w1[ks] = *(const u32x4*)(WhT + r1 + ks * 32 + kg * 8);
    }
#pragma unroll
    for (int ks = 0; ks < 32; ++ks) {
      asm volatile("" : "+v"(w0[ks]));
      asm volatile("" : "+v"(w1[ks]));
    }
  }

  // ---- stage masks to LDS: mlds[t*16+er] = masks[t][row0+er]
  for (int i = 0; i < 16; ++i) {
    int idx = i * 256 + tid;
    mlds[idx] = masks[(size_t)(idx >> 4) * BB + row0 + (idx & 15)];
  }
  if (tid < 16) mlds[TT * 16 + tid] = 0;

  const int er = tid >> 4;
  const int ec = (tid & 15) * 2;
  const int grow = row0 + er;
  const int guu = u0 + ec;

  float bs0[4], bs1[4];
#pragma unroll
  for (int gt = 0; gt < 4; ++gt) {
    bs0[gt] = bias[gt * UU + guu];
    bs1[gt] = bias[gt * UU + guu + 1];
  }

  float cv0 = init_cs[(size_t)grow * UU + guu];
  float cv1 = init_cs[(size_t)grow * UU + guu + 1];
  float hv0 = init_cs[(size_t)BB * UU + grow * UU + guu];
  float hv1 = init_cs[(size_t)BB * UU + grow * UU + guu + 1];

  const unsigned wswz = ((unsigned)(er & 7)) << 4;
  const unsigned hoff = (unsigned)er * 2048u + ((((unsigned)guu) * 2u) ^ wswz);

  { // publish h(0) (masked) into buf 0
    int m0 = masks[grow];                        // masks[0][grow]
    float s = m0 ? 0.f : 1.f;
    char* base = (char*)hglob + (size_t)g * 32768 + hoff;
    unsigned pv = ((unsigned)f2bf(hv1 * s) << 16) | f2bf(hv0 * s);
    *(unsigned*)base = pv;
  }
  __syncthreads();                               // full drain (prologue only)
  if (tid == 0) fl[sb] = 1;
  if (wave == 0) {
    unsigned v;
    do { v = __hip_atomic_load(&fl[lane & 31], __ATOMIC_RELAXED, __HIP_MEMORY_SCOPE_AGENT); }
    while (!__all(v >= 1));
  }
  __syncthreads();

  // swizzled A-frag base pointers (XOR bank swizzle bits 4-6)
  const unsigned rswz = ((unsigned)(l15 & 7)) << 4;
  const char* hp0 = hlds_c + l15 * 2048 + (((unsigned)(kg * 16 + 0)) ^ rswz);
  const char* hp1 = hlds_c + l15 * 2048 + (((unsigned)(kg * 16 + 64)) ^ rswz);

  // staging address: row = tid>>5 (j=0) / 8+(tid>>5) (j=1), 16B chunk tid&31
  const unsigned sbase = ((unsigned)(tid >> 5)) * 2048u + ((unsigned)(tid & 31)) * 16u;

  for (int t = 0; t < TT; ++t) {
    const char* gsrc = (const char*)hglob + ((size_t)((t & 1) * 8 + g)) * 32768;

    // --- issue all 8 stage loads, quarter order (q0j0,q0j1,q1j0,...)
    u32x4 sv[8];
#pragma unroll
    for (int q = 0; q < 4; ++q) {
#pragma unroll
      for (int j = 0; j < 2; ++j) {
        const char* ap = gsrc + sbase + j * 16384 + q * 512;
        asm volatile("global_load_dwordx4 %0, %1, off sc0" : "=v"(sv[q * 2 + j]) : "v"(ap));
      }
    }

    f32x4 acc0 = {0.f, 0.f, 0.f, 0.f};
    f32x4 acc1 = {0.f, 0.f, 0.f, 0.f};

    SCAN_QUARTER(0, "vmcnt(6)")
    SCAN_QUARTER(1, "vmcnt(4)")

    // --- xz(t) loads issued mid-pipeline: hidden under q2/q3 MFMA,
    //     drained by the zlds __syncthreads, used after it.
    unsigned xzv[4];
    {
      const size_t xrow = ((size_t)(t * BB + grow)) * NZ;
#pragma unroll
      for (int gt = 0; gt < 4; ++gt)
        xzv[gt] = *(const unsigned*)(xz + xrow + gt * UU + guu);
    }

    SCAN_QUARTER(2, "vmcnt(6)")   // retires l4,l5 (xz stays in flight)
    SCAN_QUARTER(3, "vmcnt(4)")   // retires l6,l7

    // --- exchange gates across waves via LDS
#pragma unroll
    for (int j = 0; j < 4; ++j) {
      zlds[wave][kg * 4 + j][l15] = acc0[j];
      zlds[wave][kg * 4 + j][16 + l15] = acc1[j];
    }
    __syncthreads();                             // drains lgkm + xz loads

    // --- gate math
    const int mcur = mlds[t * 16 + er];
    const int mnxt = mlds[(t + 1) * 16 + er];
    float z0[4], z1[4];
#pragma unroll
    for (int gt = 0; gt < 4; ++gt) {
      z0[gt] = zlds[gt][er][ec]     + bs0[gt] + bf2f((unsigned short)(xzv[gt] & 0xffffu));
      z1[gt] = zlds[gt][er][ec + 1] + bs1[gt] + bf2f((unsigned short)(xzv[gt] >> 16));
    }
    const float sm = mcur ? 0.f : 1.f;
    cv0 *= sm; cv1 *= sm;
    {
      float ig = sigm(z0[0]), fg = sigm(z0[1]), og = sigm(z0[2]), ug = tanh_(z0[3]);
      cv0 = fg * cv0 + ig * ug;
      hv0 = og * tanh_(cv0);
    }
    {
      float ig = sigm(z1[0]), fg = sigm(z1[1]), og = sigm(z1[2]), ug = tanh_(z1[3]);
      cv1 = fg * cv1 + ig * ug;
      hv1 = og * tanh_(cv1);
    }

    // --- counted publish: h store FIRST (L2), out store SECOND (stays in
    //     flight across the step boundary); vmcnt(1) = h acked.
    {
      const float sn = mnxt ? 0.f : 1.f;
      char* hdst = (char*)hglob + ((size_t)(((t + 1) & 1) * 8 + g)) * 32768 + hoff;
      unsigned pv = ((unsigned)f2bf(hv1 * sn) << 16) | f2bf(hv0 * sn);
      asm volatile("global_store_dword %0, %1, off" :: "v"(hdst), "v"(pv) : "memory");
      float* odst = out + (size_t)t * (BB * UU) + (size_t)grow * UU + guu;
      f32x2 ov = {hv0, hv1};
      asm volatile("global_store_dwordx2 %0, %1, off" :: "v"(odst), "v"(ov) : "memory");
    }
    asm volatile("s_waitcnt vmcnt(1)" ::: "memory");
    __builtin_amdgcn_sched_barrier(0);
    __builtin_amdgcn_s_barrier();                // all waves' h stores acked
    if (tid == 0) fl[sb] = (unsigned)(t + 2);    // publish step count
    if (wave == 0) {                             // parallel poll: all 32 slots
      const unsigned tgt = (unsigned)(t + 2);
      unsigned v;
      do { v = __hip_atomic_load(&fl[lane & 31], __ATOMIC_RELAXED, __HIP_MEMORY_SCOPE_AGENT); }
      while (!__all(v >= tgt));
    }
    __builtin_amdgcn_s_barrier();
  }

  // final states: [c ; h] appended after out
  float* so = out + (size_t)TT * BB * UU;
  *(f32x2*)(so + (size_t)grow * UU + guu) = (f32x2){cv0, cv1};
  *(f32x2*)(so + (size_t)BB * UU + grow * UU + guu) = (f32x2){hv0, hv1};
}

// ---------------------------------------------------------------------------
extern "C" void kernel_launch(void* const* d_in, const int* in_sizes, int n_in,
                              void* d_out, int out_size, void* d_ws, size_t ws_size,
                              hipStream_t stream) {
  const float* inputs  = (const float*)d_in[0];  // [256][128][1024]
  const float* states  = (const float*)d_in[1];  // [2][128][1024]
  const int*   masks   = (const int*)d_in[2];    // [256][128]
  const float* kernelx = (const float*)d_in[3];  // [1024][4096]
  const float* kernelh = (const float*)d_in[4];  // [1024][4096]
  const float* bias    = (const float*)d_in[5];  // [4096]
  float* out = (float*)d_out;
  char* ws = (char*)d_ws;

  unsigned* flags       = (unsigned*)ws;                                 // 2KB
  unsigned short* hglob = (unsigned short*)(ws + 65536);                 // 512KB
  unsigned short* WhT   = (unsigned short*)(ws + (size_t)2  * 1048576);  // 8MB
  unsigned short* WxT   = (unsigned short*)(ws + (size_t)10 * 1048576);  // 8MB
  unsigned short* Abf   = (unsigned short*)(ws + (size_t)18 * 1048576);  // 64MB
  unsigned short* xzbig = (unsigned short*)(ws + (size_t)82 * 1048576);  // 256MB

  k_transpose<<<dim3(64, 16), dim3(256), 0, stream>>>(kernelx, WxT);
  k_transpose<<<dim3(64, 16), dim3(256), 0, stream>>>(kernelh, WhT);
  k_convert<<<dim3(16384), dim3(256), 0, stream>>>(inputs, Abf, (TT * BB * DD) / 8);
  k_gemm_bf<<<dim3(8192), dim3(256), 0, stream>>>(Abf, WxT, xzbig);
  hipMemsetAsync(flags, 0, 2048, stream);
  k_scan<<<dim3(256), dim3(256), 0, stream>>>(states, masks, WhT, bias, xzbig,
                                              out, hglob, flags);
}

// Round 13
// 1201.254 us; speedup vs baseline: 1.2861x; 1.0010x over previous
//
#include <hip/hip_runtime.h>

// ---------------------------------------------------------------------------
// LSTM: out[t] = h_t for t in [0,256);  final (c,h) appended.
//   T=256, B=128, D=1024, U=1024, 4U=4096
// Pipeline (ws ~338MB), 3 dispatches:
//   k_prep      : [blocks 0..16383] inputs f32->bf16; [16384..17407] kernelx
//                 transpose->WxT; [17408..18431] kernelh transpose->WhT;
//                 block 0 also zeroes the scan flags (replaces memset).
//   k_gemm_bf   : xz = inputs_bf @ kernelx (m97 structure)  [unchanged]
//   k_scan      : R8 schedule (measured optimum)             [unchanged]
// ---------------------------------------------------------------------------

typedef float  f32x4 __attribute__((ext_vector_type(4)));
typedef float  f32x2 __attribute__((ext_vector_type(2)));
typedef __bf16 bf16x8 __attribute__((ext_vector_type(8)));
typedef unsigned short us8 __attribute__((ext_vector_type(8)));
typedef unsigned short us4 __attribute__((ext_vector_type(4)));
typedef unsigned int   u32x4 __attribute__((ext_vector_type(4)));

#define TT 256
#define BB 128
#define DD 1024
#define UU 1024
#define NZ 4096

typedef __attribute__((address_space(3))) unsigned       lds_u32;
typedef const __attribute__((address_space(1))) unsigned glob_u32;

__device__ __forceinline__ unsigned short f2bf(float x) {
  union { float f; unsigned u; } v; v.f = x;
  unsigned r = v.u + 0x7fffu + ((v.u >> 16) & 1u);   // RNE
  return (unsigned short)(r >> 16);
}
__device__ __forceinline__ float bf2f(unsigned short b) {
  union { unsigned u; float f; } v; v.u = ((unsigned)b) << 16;
  return v.f;
}
__device__ __forceinline__ float sigm(float x) { return 1.f / (1.f + __expf(-x)); }
__device__ __forceinline__ float tanh_(float x) { return 1.f - 2.f / (__expf(2.f * x) + 1.f); }

// ---------------- prep: convert + both transposes + flag init, one dispatch
__global__ __launch_bounds__(256) void k_prep(const float* __restrict__ inputs,
                                              unsigned short* __restrict__ Abf,
                                              const float* __restrict__ kernelx,
                                              unsigned short* __restrict__ WxT,
                                              const float* __restrict__ kernelh,
                                              unsigned short* __restrict__ WhT,
                                              unsigned* __restrict__ flags) {
  __shared__ unsigned short tile[64][72];
  const int b = blockIdx.x;
  const int t = threadIdx.x;

  if (b == 0) {                       // zero 2KB flag region (512 u32)
    flags[t] = 0;
    flags[t + 256] = 0;
  }

  if (b < 16384) {
    // ---- convert: inputs f32 -> bf16, 8 elems/thread
    const int i = b * 256 + t;        // i < 4,194,304 = TT*BB*DD/8
    const float4 a = *(const float4*)(inputs + (size_t)i * 8);
    const float4 c = *(const float4*)(inputs + (size_t)i * 8 + 4);
    us8 v;
    v[0] = f2bf(a.x); v[1] = f2bf(a.y); v[2] = f2bf(a.z); v[3] = f2bf(a.w);
    v[4] = f2bf(c.x); v[5] = f2bf(c.y); v[6] = f2bf(c.z); v[7] = f2bf(c.w);
    *(us8*)(Abf + (size_t)i * 8) = v;
    return;
  }

  // ---- transpose+convert: W f32 [1024][4096] -> W^T bf16 [4096][1024]
  const float* in          = (b < 17408) ? kernelx : kernelh;
  unsigned short* outp     = (b < 17408) ? WxT : WhT;
  const int bb = (b - 16384) & 1023;
  const int ni = bb & 63;             // 64 tiles along N=4096
  const int ki = bb >> 6;             // 16 tiles along K=1024
  const int c = t & 63, r0 = t >> 6;
#pragma unroll
  for (int rr = 0; rr < 16; ++rr) {
    int r = r0 * 16 + rr;
    tile[r][c] = f2bf(in[(size_t)(ki * 64 + r) * NZ + ni * 64 + c]);
  }
  __syncthreads();
  const int kcol = t & 63, ng = t >> 6;
#pragma unroll
  for (int cc = 0; cc < 16; ++cc) {
    int n_off = ng * 16 + cc;
    outp[(size_t)(ni * 64 + n_off) * DD + ki * 64 + kcol] = tile[kcol][n_off];
  }
}

// ---------------- xz = A_bf16[32768][1024] @ WxT^T, m97 structure (unchanged)
__global__ __launch_bounds__(256, 2) void k_gemm_bf(const unsigned short* __restrict__ A,
                                                    const unsigned short* __restrict__ Bt,
                                                    unsigned short* __restrict__ C) {
  __shared__ unsigned short Al[2][128 * 64];
  __shared__ unsigned short Bl[2][128 * 64];
  const int bx = blockIdx.x;
  const int wgid = (bx & 7) * 1024 + (bx >> 3);
  const int tm = wgid >> 5, tn = wgid & 31;
  const int tid = threadIdx.x;
  const int wave = tid >> 6, lane = tid & 63;
  const int wr = wave >> 1, wc = wave & 1;
  const int l15 = lane & 15, kg = lane >> 4;

  f32x4 acc[4][4] = {};   // [ni][mi]

  const int srow = tid >> 3;
  const int scol = (tid & 7) * 8;
  const unsigned sdst = tid * 8;

  auto stage = [&](int buf, int kt) {
#pragma unroll
    for (int i = 0; i < 4; ++i) {
      __builtin_amdgcn_global_load_lds(
          (glob_u32*)(A  + (size_t)(tm * 128 + i * 32 + srow) * DD + kt * 64 + scol),
          (lds_u32*)&Al[buf][i * 2048 + sdst], 16, 0, 0);
      __builtin_amdgcn_global_load_lds(
          (glob_u32*)(Bt + (size_t)(tn * 128 + i * 32 + srow) * DD + kt * 64 + scol),
          (lds_u32*)&Bl[buf][i * 2048 + sdst], 16, 0, 0);
    }
  };

  stage(0, 0);
  __syncthreads();

  for (int kt = 0; kt < 16; ++kt) {
    const int buf = kt & 1;
    if (kt < 15) stage(buf ^ 1, kt + 1);
#pragma unroll
    for (int ks = 0; ks < 2; ++ks) {
      bf16x8 af[4], bfr[4];
#pragma unroll
      for (int mi = 0; mi < 4; ++mi)
        af[mi] = *(const bf16x8*)&Al[buf][(wr * 64 + mi * 16 + l15) * 64 + ks * 32 + kg * 8];
#pragma unroll
      for (int ni = 0; ni < 4; ++ni)
        bfr[ni] = *(const bf16x8*)&Bl[buf][(wc * 64 + ni * 16 + l15) * 64 + ks * 32 + kg * 8];
#pragma unroll
      for (int mi = 0; mi < 4; ++mi)
#pragma unroll
        for (int ni = 0; ni < 4; ++ni)
          acc[ni][mi] = __builtin_amdgcn_mfma_f32_16x16x32_bf16(bfr[ni], af[mi], acc[ni][mi], 0, 0, 0);
    }
    __syncthreads();
  }

#pragma unroll
  for (int mi = 0; mi < 4; ++mi) {
    const size_t row = (size_t)tm * 128 + wr * 64 + mi * 16 + l15;
#pragma unroll
    for (int ni = 0; ni < 4; ++ni) {
      const size_t col = (size_t)tn * 128 + wc * 64 + ni * 16 + kg * 4;
      us4 v;
      v[0] = f2bf(acc[ni][mi][0]); v[1] = f2bf(acc[ni][mi][1]);
      v[2] = f2bf(acc[ni][mi][2]); v[3] = f2bf(acc[ni][mi][3]);
      *(us4*)(C + row * NZ + col) = v;
    }
  }
}

// ---------------- scan: 256 steps, quarter-pipelined staging + counted publish
// (R8 schedule, measured optimum — unchanged)
#define SCAN_QUARTER(Q, VMSTR)                                                  \
  {                                                                             \
    asm volatile("s_waitcnt " VMSTR ::: "memory");                              \
    __builtin_amdgcn_sched_barrier(0);                                          \
    *(u32x4*)(hlds_c + sbase + (Q) * 512)         = sv[(Q) * 2];                \
    *(u32x4*)(hlds_c + sbase + 16384 + (Q) * 512) = sv[(Q) * 2 + 1];            \
    asm volatile("s_waitcnt lgkmcnt(0)" ::: "memory");                          \
    __builtin_amdgcn_sched_barrier(0);                                          \
    __builtin_amdgcn_s_barrier();                                               \
    _Pragma("unroll")                                                           \
    for (int ks = (Q) * 8; ks < (Q) * 8 + 8; ++ks) {                            \
      const char* p = ((ks & 1) ? hp1 : hp0) + (ks >> 1) * 128;                 \
      bf16x8 a = *(const bf16x8*)p;                                             \
      acc0 = __builtin_amdgcn_mfma_f32_16x16x32_bf16(a, __builtin_bit_cast(bf16x8, w0[ks]), acc0, 0, 0, 0); \
      acc1 = __builtin_amdgcn_mfma_f32_16x16x32_bf16(a, __builtin_bit_cast(bf16x8, w1[ks]), acc1, 0, 0, 0); \
    }                                                                           \
  }

__global__ __launch_bounds__(256, 1) void k_scan(const float* __restrict__ init_cs,
                                                 const int* __restrict__ masks,
                                                 const unsigned short* __restrict__ WhT,
                                                 const float* __restrict__ bias,
                                                 const unsigned short* __restrict__ xz,
                                                 float* __restrict__ out,
                                                 unsigned short* __restrict__ hglob,
                                                 unsigned* __restrict__ flags) {
  __shared__ char  hlds_c[32768];               // 32KB h tile (swizzled layout)
  __shared__ float zlds[4][16][33];
  __shared__ int   mlds[TT * 16 + 16];          // masks [t][er], +pad

  const int tid = threadIdx.x;
  const int wave = tid >> 6, lane = tid & 63;
  const int l15 = lane & 15, kg = lane >> 4;
  const int blk = blockIdx.x;
  const int g = blk & 7;
  const int sb = blk >> 3;
  const int u0 = sb * 32;
  const int row0 = g * 16;
  unsigned* fl = flags + g * 64;                // 256B stride per group

  // ---- Wh fragments resident in registers, pinned
  u32x4 w0[32], w1[32];
  {
    const size_t r0 = (size_t)(wave * UU + u0 + l15) * DD;
    const size_t r1 = (size_t)(wave * UU + u0 + 16 + l15) * DD;
#pragma unroll
    for (int ks = 0; ks < 32; ++ks) {
      w0[ks] = *(const u32x4*)(WhT + r0 + ks * 32 + kg * 8);
      w1[ks] = *(const u32x4*)(WhT + r1 + ks * 32 + kg * 8);
    }
#pragma unroll
    for (int ks = 0; ks < 32; ++ks) {
      asm volatile("" : "+v"(w0[ks]));
      asm volatile("" : "+v"(w1[ks]));
    }
  }

  // ---- stage masks to LDS: mlds[t*16+er] = masks[t][row0+er]
  for (int i = 0; i < 16; ++i) {
    int idx = i * 256 + tid;
    mlds[idx] = masks[(size_t)(idx >> 4) * BB + row0 + (idx & 15)];
  }
  if (tid < 16) mlds[TT * 16 + tid] = 0;

  const int er = tid >> 4;
  const int ec = (tid & 15) * 2;
  const int grow = row0 + er;
  const int guu = u0 + ec;

  float bs0[4], bs1[4];
#pragma unroll
  for (int gt = 0; gt < 4; ++gt) {
    bs0[gt] = bias[gt * UU + guu];
    bs1[gt] = bias[gt * UU + guu + 1];
  }

  float cv0 = init_cs[(size_t)grow * UU + guu];
  float cv1 = init_cs[(size_t)grow * UU + guu + 1];
  float hv0 = init_cs[(size_t)BB * UU + grow * UU + guu];
  float hv1 = init_cs[(size_t)BB * UU + grow * UU + guu + 1];

  const unsigned wswz = ((unsigned)(er & 7)) << 4;
  const unsigned hoff = (unsigned)er * 2048u + ((((unsigned)guu) * 2u) ^ wswz);

  { // publish h(0) (masked) into buf 0
    int m0 = masks[grow];                        // masks[0][grow]
    float s = m0 ? 0.f : 1.f;
    char* base = (char*)hglob + (size_t)g * 32768 + hoff;
    unsigned pv = ((unsigned)f2bf(hv1 * s) << 16) | f2bf(hv0 * s);
    *(unsigned*)base = pv;
  }
  __syncthreads();                               // full drain (prologue only)
  if (tid == 0) fl[sb] = 1;
  if (wave == 0) {
    unsigned v;
    do { v = __hip_atomic_load(&fl[lane & 31], __ATOMIC_RELAXED, __HIP_MEMORY_SCOPE_AGENT); }
    while (!__all(v >= 1));
  }
  __syncthreads();

  // swizzled A-frag base pointers (XOR bank swizzle bits 4-6)
  const unsigned rswz = ((unsigned)(l15 & 7)) << 4;
  const char* hp0 = hlds_c + l15 * 2048 + (((unsigned)(kg * 16 + 0)) ^ rswz);
  const char* hp1 = hlds_c + l15 * 2048 + (((unsigned)(kg * 16 + 64)) ^ rswz);

  // staging address: row = tid>>5 (j=0) / 8+(tid>>5) (j=1), 16B chunk tid&31
  const unsigned sbase = ((unsigned)(tid >> 5)) * 2048u + ((unsigned)(tid & 31)) * 16u;

  for (int t = 0; t < TT; ++t) {
    const char* gsrc = (const char*)hglob + ((size_t)((t & 1) * 8 + g)) * 32768;

    // --- issue all 8 stage loads, quarter order (q0j0,q0j1,q1j0,...)
    u32x4 sv[8];
#pragma unroll
    for (int q = 0; q < 4; ++q) {
#pragma unroll
      for (int j = 0; j < 2; ++j) {
        const char* ap = gsrc + sbase + j * 16384 + q * 512;
        asm volatile("global_load_dwordx4 %0, %1, off sc0" : "=v"(sv[q * 2 + j]) : "v"(ap));
      }
    }

    f32x4 acc0 = {0.f, 0.f, 0.f, 0.f};
    f32x4 acc1 = {0.f, 0.f, 0.f, 0.f};

    SCAN_QUARTER(0, "vmcnt(6)")
    SCAN_QUARTER(1, "vmcnt(4)")

    // --- xz(t) loads issued mid-pipeline: hidden under q2/q3 MFMA,
    //     drained by the zlds __syncthreads, used after it.
    unsigned xzv[4];
    {
      const size_t xrow = ((size_t)(t * BB + grow)) * NZ;
#pragma unroll
      for (int gt = 0; gt < 4; ++gt)
        xzv[gt] = *(const unsigned*)(xz + xrow + gt * UU + guu);
    }

    SCAN_QUARTER(2, "vmcnt(6)")   // retires l4,l5 (xz stays in flight)
    SCAN_QUARTER(3, "vmcnt(4)")   // retires l6,l7

    // --- exchange gates across waves via LDS
#pragma unroll
    for (int j = 0; j < 4; ++j) {
      zlds[wave][kg * 4 + j][l15] = acc0[j];
      zlds[wave][kg * 4 + j][16 + l15] = acc1[j];
    }
    __syncthreads();                             // drains lgkm + xz loads

    // --- gate math
    const int mcur = mlds[t * 16 + er];
    const int mnxt = mlds[(t + 1) * 16 + er];
    float z0[4], z1[4];
#pragma unroll
    for (int gt = 0; gt < 4; ++gt) {
      z0[gt] = zlds[gt][er][ec]     + bs0[gt] + bf2f((unsigned short)(xzv[gt] & 0xffffu));
      z1[gt] = zlds[gt][er][ec + 1] + bs1[gt] + bf2f((unsigned short)(xzv[gt] >> 16));
    }
    const float sm = mcur ? 0.f : 1.f;
    cv0 *= sm; cv1 *= sm;
    {
      float ig = sigm(z0[0]), fg = sigm(z0[1]), og = sigm(z0[2]), ug = tanh_(z0[3]);
      cv0 = fg * cv0 + ig * ug;
      hv0 = og * tanh_(cv0);
    }
    {
      float ig = sigm(z1[0]), fg = sigm(z1[1]), og = sigm(z1[2]), ug = tanh_(z1[3]);
      cv1 = fg * cv1 + ig * ug;
      hv1 = og * tanh_(cv1);
    }

    // --- counted publish: h store FIRST (L2), out store SECOND (stays in
    //     flight across the step boundary); vmcnt(1) = h acked.
    {
      const float sn = mnxt ? 0.f : 1.f;
      char* hdst = (char*)hglob + ((size_t)(((t + 1) & 1) * 8 + g)) * 32768 + hoff;
      unsigned pv = ((unsigned)f2bf(hv1 * sn) << 16) | f2bf(hv0 * sn);
      asm volatile("global_store_dword %0, %1, off" :: "v"(hdst), "v"(pv) : "memory");
      float* odst = out + (size_t)t * (BB * UU) + (size_t)grow * UU + guu;
      f32x2 ov = {hv0, hv1};
      asm volatile("global_store_dwordx2 %0, %1, off" :: "v"(odst), "v"(ov) : "memory");
    }
    asm volatile("s_waitcnt vmcnt(1)" ::: "memory");
    __builtin_amdgcn_sched_barrier(0);
    __builtin_amdgcn_s_barrier();                // all waves' h stores acked
    if (tid == 0) fl[sb] = (unsigned)(t + 2);    // publish step count
    if (wave == 0) {                             // parallel poll: all 32 slots
      const unsigned tgt = (unsigned)(t + 2);
      unsigned v;
      do { v = __hip_atomic_load(&fl[lane & 31], __ATOMIC_RELAXED, __HIP_MEMORY_SCOPE_AGENT); }
      while (!__all(v >= tgt));
    }
    __builtin_amdgcn_s_barrier();
  }

  // final states: [c ; h] appended after out
  float* so = out + (size_t)TT * BB * UU;
  *(f32x2*)(so + (size_t)grow * UU + guu) = (f32x2){cv0, cv1};
  *(f32x2*)(so + (size_t)BB * UU + grow * UU + guu) = (f32x2){hv0, hv1};
}

// ---------------------------------------------------------------------------
extern "C" void kernel_launch(void* const* d_in, const int* in_sizes, int n_in,
                              void* d_out, int out_size, void* d_ws, size_t ws_size,
                              hipStream_t stream) {
  const float* inputs  = (const float*)d_in[0];  // [256][128][1024]
  const float* states  = (const float*)d_in[1];  // [2][128][1024]
  const int*   masks   = (const int*)d_in[2];    // [256][128]
  const float* kernelx = (const float*)d_in[3];  // [1024][4096]
  const float* kernelh = (const float*)d_in[4];  // [1024][4096]
  const float* bias    = (const float*)d_in[5];  // [4096]
  float* out = (float*)d_out;
  char* ws = (char*)d_ws;

  unsigned* flags       = (unsigned*)ws;                                 // 2KB
  unsigned short* hglob = (unsigned short*)(ws + 65536);                 // 512KB
  unsigned short* WhT   = (unsigned short*)(ws + (size_t)2  * 1048576);  // 8MB
  unsigned short* WxT   = (unsigned short*)(ws + (size_t)10 * 1048576);  // 8MB
  unsigned short* Abf   = (unsigned short*)(ws + (size_t)18 * 1048576);  // 64MB
  unsigned short* xzbig = (unsigned short*)(ws + (size_t)82 * 1048576);  // 256MB

  k_prep<<<dim3(18432), dim3(256), 0, stream>>>(inputs, Abf, kernelx, WxT,
                                                kernelh, WhT, flags);
  k_gemm_bf<<<dim3(8192), dim3(256), 0, stream>>>(Abf, WxT, xzbig);
  k_scan<<<dim3(256), dim3(256), 0, stream>>>(states, masks, WhT, bias, xzbig,
                                              out, hglob, flags);
}

// Round 14
// 1085.636 us; speedup vs baseline: 1.4231x; 1.1065x over previous
//
#include <hip/hip_runtime.h>

// ---------------------------------------------------------------------------
// LSTM: out[t] = h_t for t in [0,256);  final (c,h) appended.
//   T=256, B=128, D=1024, U=1024, 4U=4096
// Pipeline (ws ~338MB), 3 dispatches:
//   k_prep      : convert inputs f32->bf16 + both W transposes + flag init
//   k_gemm_bf   : xz = inputs_bf @ kernelx. NEW 256x256 tile, 512 thr/8 waves,
//                 128KB LDS dbuf, 1 exact vmcnt(0)+barrier per K-step (stage
//                 issued AFTER the barrier -> full MFMA phase to land),
//                 chunk-XOR LDS swizzle (pre-swizzled global src, rule #21).
//   k_scan      : R8 schedule (measured optimum) — byte-identical.
// ---------------------------------------------------------------------------

typedef float  f32x4 __attribute__((ext_vector_type(4)));
typedef float  f32x2 __attribute__((ext_vector_type(2)));
typedef __bf16 bf16x8 __attribute__((ext_vector_type(8)));
typedef unsigned short us8 __attribute__((ext_vector_type(8)));
typedef unsigned short us4 __attribute__((ext_vector_type(4)));
typedef unsigned int   u32x4 __attribute__((ext_vector_type(4)));

#define TT 256
#define BB 128
#define DD 1024
#define UU 1024
#define NZ 4096

typedef __attribute__((address_space(3))) unsigned       lds_u32;
typedef const __attribute__((address_space(1))) unsigned glob_u32;

__device__ __forceinline__ unsigned short f2bf(float x) {
  union { float f; unsigned u; } v; v.f = x;
  unsigned r = v.u + 0x7fffu + ((v.u >> 16) & 1u);   // RNE
  return (unsigned short)(r >> 16);
}
__device__ __forceinline__ float bf2f(unsigned short b) {
  union { unsigned u; float f; } v; v.u = ((unsigned)b) << 16;
  return v.f;
}
__device__ __forceinline__ float sigm(float x) { return 1.f / (1.f + __expf(-x)); }
__device__ __forceinline__ float tanh_(float x) { return 1.f - 2.f / (__expf(2.f * x) + 1.f); }

// ---------------- prep: convert + both transposes + flag init, one dispatch
__global__ __launch_bounds__(256) void k_prep(const float* __restrict__ inputs,
                                              unsigned short* __restrict__ Abf,
                                              const float* __restrict__ kernelx,
                                              unsigned short* __restrict__ WxT,
                                              const float* __restrict__ kernelh,
                                              unsigned short* __restrict__ WhT,
                                              unsigned* __restrict__ flags) {
  __shared__ unsigned short tile[64][72];
  const int b = blockIdx.x;
  const int t = threadIdx.x;

  if (b == 0) {                       // zero 2KB flag region (512 u32)
    flags[t] = 0;
    flags[t + 256] = 0;
  }

  if (b < 16384) {
    // ---- convert: inputs f32 -> bf16, 8 elems/thread
    const int i = b * 256 + t;        // i < 4,194,304 = TT*BB*DD/8
    const float4 a = *(const float4*)(inputs + (size_t)i * 8);
    const float4 c = *(const float4*)(inputs + (size_t)i * 8 + 4);
    us8 v;
    v[0] = f2bf(a.x); v[1] = f2bf(a.y); v[2] = f2bf(a.z); v[3] = f2bf(a.w);
    v[4] = f2bf(c.x); v[5] = f2bf(c.y); v[6] = f2bf(c.z); v[7] = f2bf(c.w);
    *(us8*)(Abf + (size_t)i * 8) = v;
    return;
  }

  // ---- transpose+convert: W f32 [1024][4096] -> W^T bf16 [4096][1024]
  const float* in          = (b < 17408) ? kernelx : kernelh;
  unsigned short* outp     = (b < 17408) ? WxT : WhT;
  const int bb = (b - 16384) & 1023;
  const int ni = bb & 63;             // 64 tiles along N=4096
  const int ki = bb >> 6;             // 16 tiles along K=1024
  const int c = t & 63, r0 = t >> 6;
#pragma unroll
  for (int rr = 0; rr < 16; ++rr) {
    int r = r0 * 16 + rr;
    tile[r][c] = f2bf(in[(size_t)(ki * 64 + r) * NZ + ni * 64 + c]);
  }
  __syncthreads();
  const int kcol = t & 63, ng = t >> 6;
#pragma unroll
  for (int cc = 0; cc < 16; ++cc) {
    int n_off = ng * 16 + cc;
    outp[(size_t)(ni * 64 + n_off) * DD + ki * 64 + kcol] = tile[kcol][n_off];
  }
}

// ---------------- xz = A_bf16[32768][1024] @ WxT^T, 256x256 tile, 512 threads
// grid 2048 = 128 m-tiles x 16 n-tiles, XCD swizzle (2048 % 8 == 0).
// 8 waves = 2M x 4N; per-wave output 128x64 (8 m-frags x 4 n-frags).
// LDS: [2 dbuf][256 rows][64 k] bf16 per matrix = 128KB total, 1 block/CU.
// Swizzle: LDS[row][chunk j] holds global chunk (j ^ (row&7)); writers
// pre-swizzle the GLOBAL source (gll16 dst stays linear), readers XOR.
// Schedule: per K-step {exact vmcnt(0); s_barrier; stage(next); 64 MFMA}.
// Hazards: RAW on buf ensured by vmcnt(0)+barrier (stage for buf issued in
// the previous step, aged one full MFMA phase); WAR on buf^1 ensured because
// its readers finished before the barrier all waves just crossed.
__global__ __launch_bounds__(512, 2) void k_gemm_bf(const unsigned short* __restrict__ A,
                                                    const unsigned short* __restrict__ Bt,
                                                    unsigned short* __restrict__ C) {
  __shared__ unsigned short Al[2][16384];
  __shared__ unsigned short Bl[2][16384];
  const int bx = blockIdx.x;
  const int wgid = (bx & 7) * 256 + (bx >> 3);
  const int tm = wgid >> 4, tn = wgid & 15;
  const int tid = threadIdx.x;
  const int wave = tid >> 6, lane = tid & 63;
  const int wr = wave >> 2, wc = wave & 3;
  const int l15 = lane & 15, kg = lane >> 4;
  const int r3 = l15 & 7;

  f32x4 acc[4][8] = {};   // [nj][mi]

  // staging: load i covers tile rows [i*64, i*64+64)
  const int srow = tid >> 3;                       // 0..63 row within load-round
  const int sj   = (tid & 7) ^ (srow & 7);         // pre-swizzled global chunk
  const unsigned sdst = (unsigned)tid * 8;         // LDS elements (linear)

  auto stage = [&](int buf, int kt) {
#pragma unroll
    for (int i = 0; i < 4; ++i)
      __builtin_amdgcn_global_load_lds(
          (glob_u32*)(A + (size_t)(tm * 256 + i * 64 + srow) * DD + kt * 64 + sj * 8),
          (lds_u32*)&Al[buf][i * 4096 + sdst], 16, 0, 0);
#pragma unroll
    for (int i = 0; i < 4; ++i)
      __builtin_amdgcn_global_load_lds(
          (glob_u32*)(Bt + (size_t)(tn * 256 + i * 64 + srow) * DD + kt * 64 + sj * 8),
          (lds_u32*)&Bl[buf][i * 4096 + sdst], 16, 0, 0);
  };

  // reader byte offsets: row*128 + ((ks*4|kg) ^ r3)*16
  const unsigned aoff0 = ((unsigned)(wr * 128 + l15)) * 128u + ((unsigned)(kg ^ r3)) * 16u;
  const unsigned aoff1 = ((unsigned)(wr * 128 + l15)) * 128u + ((unsigned)((4 | kg) ^ r3)) * 16u;
  const unsigned boff0 = ((unsigned)(wc * 64 + l15)) * 128u + ((unsigned)(kg ^ r3)) * 16u;
  const unsigned boff1 = ((unsigned)(wc * 64 + l15)) * 128u + ((unsigned)((4 | kg) ^ r3)) * 16u;

  stage(0, 0);

  for (int kt = 0; kt < 16; ++kt) {
    const int buf = kt & 1;
    // exact wait: the only outstanding VMEM is this buf's 8 staging loads
    asm volatile("s_waitcnt vmcnt(0)" ::: "memory");
    __builtin_amdgcn_sched_barrier(0);
    __builtin_amdgcn_s_barrier();
    if (kt < 15) stage(buf ^ 1, kt + 1);

    const char* Ab = (const char*)&Al[buf][0];
    const char* Bb = (const char*)&Bl[buf][0];
#pragma unroll
    for (int ks = 0; ks < 2; ++ks) {
      const unsigned ao = ks ? aoff1 : aoff0;
      const unsigned bo = ks ? boff1 : boff0;
      bf16x8 af[8], bfr[4];
#pragma unroll
      for (int mi = 0; mi < 8; ++mi) af[mi] = *(const bf16x8*)(Ab + ao + mi * 2048);
#pragma unroll
      for (int nj = 0; nj < 4; ++nj) bfr[nj] = *(const bf16x8*)(Bb + bo + nj * 2048);
#pragma unroll
      for (int nj = 0; nj < 4; ++nj)
#pragma unroll
        for (int mi = 0; mi < 8; ++mi)
          acc[nj][mi] = __builtin_amdgcn_mfma_f32_16x16x32_bf16(bfr[nj], af[mi], acc[nj][mi], 0, 0, 0);
    }
  }

  // C-store: row = m (l15), 4 consecutive n-cols per acc (kg*4+j) -> 8B stores
#pragma unroll
  for (int mi = 0; mi < 8; ++mi) {
    const size_t row = (size_t)tm * 256 + wr * 128 + mi * 16 + l15;
#pragma unroll
    for (int nj = 0; nj < 4; ++nj) {
      const size_t col = (size_t)tn * 256 + wc * 64 + nj * 16 + kg * 4;
      us4 v;
      v[0] = f2bf(acc[nj][mi][0]); v[1] = f2bf(acc[nj][mi][1]);
      v[2] = f2bf(acc[nj][mi][2]); v[3] = f2bf(acc[nj][mi][3]);
      *(us4*)(C + row * NZ + col) = v;
    }
  }
}

// ---------------- scan: 256 steps, quarter-pipelined staging + counted publish
// (R8 schedule, measured optimum — unchanged)
#define SCAN_QUARTER(Q, VMSTR)                                                  \
  {                                                                             \
    asm volatile("s_waitcnt " VMSTR ::: "memory");                              \
    __builtin_amdgcn_sched_barrier(0);                                          \
    *(u32x4*)(hlds_c + sbase + (Q) * 512)         = sv[(Q) * 2];                \
    *(u32x4*)(hlds_c + sbase + 16384 + (Q) * 512) = sv[(Q) * 2 + 1];            \
    asm volatile("s_waitcnt lgkmcnt(0)" ::: "memory");                          \
    __builtin_amdgcn_sched_barrier(0);                                          \
    __builtin_amdgcn_s_barrier();                                               \
    _Pragma("unroll")                                                           \
    for (int ks = (Q) * 8; ks < (Q) * 8 + 8; ++ks) {                            \
      const char* p = ((ks & 1) ? hp1 : hp0) + (ks >> 1) * 128;                 \
      bf16x8 a = *(const bf16x8*)p;                                             \
      acc0 = __builtin_amdgcn_mfma_f32_16x16x32_bf16(a, __builtin_bit_cast(bf16x8, w0[ks]), acc0, 0, 0, 0); \
      acc1 = __builtin_amdgcn_mfma_f32_16x16x32_bf16(a, __builtin_bit_cast(bf16x8, w1[ks]), acc1, 0, 0, 0); \
    }                                                                           \
  }

__global__ __launch_bounds__(256, 1) void k_scan(const float* __restrict__ init_cs,
                                                 const int* __restrict__ masks,
                                                 const unsigned short* __restrict__ WhT,
                                                 const float* __restrict__ bias,
                                                 const unsigned short* __restrict__ xz,
                                                 float* __restrict__ out,
                                                 unsigned short* __restrict__ hglob,
                                                 unsigned* __restrict__ flags) {
  __shared__ char  hlds_c[32768];               // 32KB h tile (swizzled layout)
  __shared__ float zlds[4][16][33];
  __shared__ int   mlds[TT * 16 + 16];          // masks [t][er], +pad

  const int tid = threadIdx.x;
  const int wave = tid >> 6, lane = tid & 63;
  const int l15 = lane & 15, kg = lane >> 4;
  const int blk = blockIdx.x;
  const int g = blk & 7;
  const int sb = blk >> 3;
  const int u0 = sb * 32;
  const int row0 = g * 16;
  unsigned* fl = flags + g * 64;                // 256B stride per group

  // ---- Wh fragments resident in registers, pinned
  u32x4 w0[32], w1[32];
  {
    const size_t r0 = (size_t)(wave * UU + u0 + l15) * DD;
    const size_t r1 = (size_t)(wave * UU + u0 + 16 + l15) * DD;
#pragma unroll
    for (int ks = 0; ks < 32; ++ks) {
      w0[ks] = *(const u32x4*)(WhT + r0 + ks * 32 + kg * 8);
      w1[ks] = *(const u32x4*)(WhT + r1 + ks * 32 + kg * 8);
    }
#pragma unroll
    for (int ks = 0; ks < 32; ++ks) {
      asm volatile("" : "+v"(w0[ks]));
      asm volatile("" : "+v"(w1[ks]));
    }
  }

  // ---- stage masks to LDS: mlds[t*16+er] = masks[t][row0+er]
  for (int i = 0; i < 16; ++i) {
    int idx = i * 256 + tid;
    mlds[idx] = masks[(size_t)(idx >> 4) * BB + row0 + (idx & 15)];
  }
  if (tid < 16) mlds[TT * 16 + tid] = 0;

  const int er = tid >> 4;
  const int ec = (tid & 15) * 2;
  const int grow = row0 + er;
  const int guu = u0 + ec;

  float bs0[4], bs1[4];
#pragma unroll
  for (int gt = 0; gt < 4; ++gt) {
    bs0[gt] = bias[gt * UU + guu];
    bs1[gt] = bias[gt * UU + guu + 1];
  }

  float cv0 = init_cs[(size_t)grow * UU + guu];
  float cv1 = init_cs[(size_t)grow * UU + guu + 1];
  float hv0 = init_cs[(size_t)BB * UU + grow * UU + guu];
  float hv1 = init_cs[(size_t)BB * UU + grow * UU + guu + 1];

  const unsigned wswz = ((unsigned)(er & 7)) << 4;
  const unsigned hoff = (unsigned)er * 2048u + ((((unsigned)guu) * 2u) ^ wswz);

  { // publish h(0) (masked) into buf 0
    int m0 = masks[grow];                        // masks[0][grow]
    float s = m0 ? 0.f : 1.f;
    char* base = (char*)hglob + (size_t)g * 32768 + hoff;
    unsigned pv = ((unsigned)f2bf(hv1 * s) << 16) | f2bf(hv0 * s);
    *(unsigned*)base = pv;
  }
  __syncthreads();                               // full drain (prologue only)
  if (tid == 0) fl[sb] = 1;
  if (wave == 0) {
    unsigned v;
    do { v = __hip_atomic_load(&fl[lane & 31], __ATOMIC_RELAXED, __HIP_MEMORY_SCOPE_AGENT); }
    while (!__all(v >= 1));
  }
  __syncthreads();

  // swizzled A-frag base pointers (XOR bank swizzle bits 4-6)
  const unsigned rswz = ((unsigned)(l15 & 7)) << 4;
  const char* hp0 = hlds_c + l15 * 2048 + (((unsigned)(kg * 16 + 0)) ^ rswz);
  const char* hp1 = hlds_c + l15 * 2048 + (((unsigned)(kg * 16 + 64)) ^ rswz);

  // staging address: row = tid>>5 (j=0) / 8+(tid>>5) (j=1), 16B chunk tid&31
  const unsigned sbase = ((unsigned)(tid >> 5)) * 2048u + ((unsigned)(tid & 31)) * 16u;

  for (int t = 0; t < TT; ++t) {
    const char* gsrc = (const char*)hglob + ((size_t)((t & 1) * 8 + g)) * 32768;

    // --- issue all 8 stage loads, quarter order (q0j0,q0j1,q1j0,...)
    u32x4 sv[8];
#pragma unroll
    for (int q = 0; q < 4; ++q) {
#pragma unroll
      for (int j = 0; j < 2; ++j) {
        const char* ap = gsrc + sbase + j * 16384 + q * 512;
        asm volatile("global_load_dwordx4 %0, %1, off sc0" : "=v"(sv[q * 2 + j]) : "v"(ap));
      }
    }

    f32x4 acc0 = {0.f, 0.f, 0.f, 0.f};
    f32x4 acc1 = {0.f, 0.f, 0.f, 0.f};

    SCAN_QUARTER(0, "vmcnt(6)")
    SCAN_QUARTER(1, "vmcnt(4)")

    // --- xz(t) loads issued mid-pipeline: hidden under q2/q3 MFMA,
    //     drained by the zlds __syncthreads, used after it.
    unsigned xzv[4];
    {
      const size_t xrow = ((size_t)(t * BB + grow)) * NZ;
#pragma unroll
      for (int gt = 0; gt < 4; ++gt)
        xzv[gt] = *(const unsigned*)(xz + xrow + gt * UU + guu);
    }

    SCAN_QUARTER(2, "vmcnt(6)")   // retires l4,l5 (xz stays in flight)
    SCAN_QUARTER(3, "vmcnt(4)")   // retires l6,l7

    // --- exchange gates across waves via LDS
#pragma unroll
    for (int j = 0; j < 4; ++j) {
      zlds[wave][kg * 4 + j][l15] = acc0[j];
      zlds[wave][kg * 4 + j][16 + l15] = acc1[j];
    }
    __syncthreads();                             // drains lgkm + xz loads

    // --- gate math
    const int mcur = mlds[t * 16 + er];
    const int mnxt = mlds[(t + 1) * 16 + er];
    float z0[4], z1[4];
#pragma unroll
    for (int gt = 0; gt < 4; ++gt) {
      z0[gt] = zlds[gt][er][ec]     + bs0[gt] + bf2f((unsigned short)(xzv[gt] & 0xffffu));
      z1[gt] = zlds[gt][er][ec + 1] + bs1[gt] + bf2f((unsigned short)(xzv[gt] >> 16));
    }
    const float sm = mcur ? 0.f : 1.f;
    cv0 *= sm; cv1 *= sm;
    {
      float ig = sigm(z0[0]), fg = sigm(z0[1]), og = sigm(z0[2]), ug = tanh_(z0[3]);
      cv0 = fg * cv0 + ig * ug;
      hv0 = og * tanh_(cv0);
    }
    {
      float ig = sigm(z1[0]), fg = sigm(z1[1]), og = sigm(z1[2]), ug = tanh_(z1[3]);
      cv1 = fg * cv1 + ig * ug;
      hv1 = og * tanh_(cv1);
    }

    // --- counted publish: h store FIRST (L2), out store SECOND (stays in
    //     flight across the step boundary); vmcnt(1) = h acked.
    {
      const float sn = mnxt ? 0.f : 1.f;
      char* hdst = (char*)hglob + ((size_t)(((t + 1) & 1) * 8 + g)) * 32768 + hoff;
      unsigned pv = ((unsigned)f2bf(hv1 * sn) << 16) | f2bf(hv0 * sn);
      asm volatile("global_store_dword %0, %1, off" :: "v"(hdst), "v"(pv) : "memory");
      float* odst = out + (size_t)t * (BB * UU) + (size_t)grow * UU + guu;
      f32x2 ov = {hv0, hv1};
      asm volatile("global_store_dwordx2 %0, %1, off" :: "v"(odst), "v"(ov) : "memory");
    }
    asm volatile("s_waitcnt vmcnt(1)" ::: "memory");
    __builtin_amdgcn_sched_barrier(0);
    __builtin_amdgcn_s_barrier();                // all waves' h stores acked
    if (tid == 0) fl[sb] = (unsigned)(t + 2);    // publish step count
    if (wave == 0) {                             // parallel poll: all 32 slots
      const unsigned tgt = (unsigned)(t + 2);
      unsigned v;
      do { v = __hip_atomic_load(&fl[lane & 31], __ATOMIC_RELAXED, __HIP_MEMORY_SCOPE_AGENT); }
      while (!__all(v >= tgt));
    }
    __builtin_amdgcn_s_barrier();
  }

  // final states: [c ; h] appended after out
  float* so = out + (size_t)TT * BB * UU;
  *(f32x2*)(so + (size_t)grow * UU + guu) = (f32x2){cv0, cv1};
  *(f32x2*)(so + (size_t)BB * UU + grow * UU + guu) = (f32x2){hv0, hv1};
}

// ---------------------------------------------------------------------------
extern "C" void kernel_launch(void* const* d_in, const int* in_sizes, int n_in,
                              void* d_out, int out_size, void* d_ws, size_t ws_size,
                              hipStream_t stream) {
  const float* inputs  = (const float*)d_in[0];  // [256][128][1024]
  const float* states  = (const float*)d_in[1];  // [2][128][1024]
  const int*   masks   = (const int*)d_in[2];    // [256][128]
  const float* kernelx = (const float*)d_in[3];  // [1024][4096]
  const float* kernelh = (const float*)d_in[4];  // [1024][4096]
  const float* bias    = (const float*)d_in[5];  // [4096]
  float* out = (float*)d_out;
  char* ws = (char*)d_ws;

  unsigned* flags       = (unsigned*)ws;                                 // 2KB
  unsigned short* hglob = (unsigned short*)(ws + 65536);                 // 512KB
  unsigned short* WhT   = (unsigned short*)(ws + (size_t)2  * 1048576);  // 8MB
  unsigned short* WxT   = (unsigned short*)(ws + (size_t)10 * 1048576);  // 8MB
  unsigned short* Abf   = (unsigned short*)(ws + (size_t)18 * 1048576);  // 64MB
  unsigned short* xzbig = (unsigned short*)(ws + (size_t)82 * 1048576);  // 256MB

  k_prep<<<dim3(18432), dim3(256), 0, stream>>>(inputs, Abf, kernelx, WxT,
                                                kernelh, WhT, flags);
  k_gemm_bf<<<dim3(2048), dim3(512), 0, stream>>>(Abf, WxT, xzbig);
  k_scan<<<dim3(256), dim3(256), 0, stream>>>(states, masks, WhT, bias, xzbig,
                                              out, hglob, flags);
}